// Round 4
// baseline (661.012 us; speedup 1.0000x reference)
//
#include <hip/hip_runtime.h>

#define THREADS 256
#define SCAN_BLK 1024
#define HB 32          // histogram blocks (src node ranges)
#define K1_BLK 512

typedef __attribute__((ext_vector_type(8))) short short8;
typedef __attribute__((ext_vector_type(4))) float floatx4;

__device__ __forceinline__ ushort f2bf(float f) {
    union { float f; uint u; } v; v.f = f;
    uint u = v.u;
    return (ushort)((u + 0x7FFFu + ((u >> 16) & 1u)) >> 16);   // RNE
}
__device__ __forceinline__ float bf_lo(uint u) {
    union { uint u; float f; } v; v.u = u << 16; return v.f;
}
__device__ __forceinline__ float bf_hi(uint u) {
    union { uint u; float f; } v; v.u = u & 0xFFFF0000u; return v.f;
}

// ====== K1 (fused): blocks [0,HB) = src-range LDS histogram -> norm_out (no atomics)
//                    blocks [HB,..) = dst rank: rank[e] = atomicAdd(cnt_in[dst[e]],1)
__global__ __launch_bounds__(K1_BLK) void k1_kernel(const int* __restrict__ src,
                                                    const int* __restrict__ dst,
                                                    int* __restrict__ cnt_in,
                                                    int* __restrict__ rank,
                                                    float* __restrict__ norm_out,
                                                    int n, int E) {
    if (blockIdx.x < HB) {
        __shared__ uint cnt[3136];                 // ceil(100000/32)=3125
        const int Rsz = (n + HB - 1) / HB;
        const int lo  = blockIdx.x * Rsz;
        const int R   = min(n - lo, Rsz);
        if (R <= 0) return;
        for (int i = threadIdx.x; i < R; i += K1_BLK) cnt[i] = 0;
        __syncthreads();
        const int E4 = E >> 2;
        const int4* s4 = (const int4*)src;
        for (int i = threadIdx.x; i < E4; i += K1_BLK) {
            int4 v = s4[i];
            if ((unsigned)(v.x - lo) < (unsigned)R) atomicAdd(&cnt[v.x - lo], 1u);
            if ((unsigned)(v.y - lo) < (unsigned)R) atomicAdd(&cnt[v.y - lo], 1u);
            if ((unsigned)(v.z - lo) < (unsigned)R) atomicAdd(&cnt[v.z - lo], 1u);
            if ((unsigned)(v.w - lo) < (unsigned)R) atomicAdd(&cnt[v.w - lo], 1u);
        }
        for (int e = (E4 << 2) + threadIdx.x; e < E; e += K1_BLK) {
            int s = src[e];
            if ((unsigned)(s - lo) < (unsigned)R) atomicAdd(&cnt[s - lo], 1u);
        }
        __syncthreads();
        for (int i = threadIdx.x; i < R; i += K1_BLK)
            norm_out[lo + i] = rsqrtf((float)max((int)cnt[i], 1));
    } else {
        const int t  = (blockIdx.x - HB) * K1_BLK + threadIdx.x;
        const int e0 = t * 4;
        if (e0 + 4 <= E) {
            int4 d4 = *(const int4*)(dst + e0);
            int r0 = atomicAdd(&cnt_in[d4.x], 1);
            int r1 = atomicAdd(&cnt_in[d4.y], 1);
            int r2 = atomicAdd(&cnt_in[d4.z], 1);
            int r3 = atomicAdd(&cnt_in[d4.w], 1);
            int4 r; r.x = r0; r.y = r1; r.z = r2; r.w = r3;
            *(int4*)(rank + e0) = r;
        } else if (e0 < E) {
            for (int e = e0; e < E; ++e) rank[e] = atomicAdd(&cnt_in[dst[e]], 1);
        }
    }
}

// ====== exclusive scan of cnt_in -> row_off; phase3 also emits norm_in ======
__global__ void scan_phase1(const int* __restrict__ cnt, int* __restrict__ blk_sums, int n) {
    int base = blockIdx.x * SCAN_BLK;
    int t = threadIdx.x;
    int sum = 0;
    for (int i = t; i < SCAN_BLK; i += THREADS) {
        int idx = base + i;
        sum += (idx < n) ? cnt[idx] : 0;
    }
    __shared__ int wsum[4];
    for (int off = 32; off > 0; off >>= 1) sum += __shfl_down(sum, off);
    if ((t & 63) == 0) wsum[t >> 6] = sum;
    __syncthreads();
    if (t == 0) blk_sums[blockIdx.x] = wsum[0] + wsum[1] + wsum[2] + wsum[3];
}

__global__ void scan_phase2(int* __restrict__ blk_sums, int nb) {
    __shared__ int s[1024];
    int t = threadIdx.x;
    s[t] = (t < nb) ? blk_sums[t] : 0;
    __syncthreads();
    for (int off = 1; off < 1024; off <<= 1) {
        int v = s[t];
        if (t >= off) v += s[t - off];
        __syncthreads();
        s[t] = v;
        __syncthreads();
    }
    if (t < nb) blk_sums[t] = (t == 0) ? 0 : s[t - 1];
}

__global__ void scan_phase3(const int* __restrict__ cnt, const int* __restrict__ blk_sums,
                            int* __restrict__ row_off, float* __restrict__ norm_in,
                            int n, int E) {
    __shared__ int ts[THREADS];
    int b = blockIdx.x, t = threadIdx.x;
    int base = b * SCAN_BLK + t * 4;
    int local[4], val[4]; int s = 0;
    #pragma unroll
    for (int k = 0; k < 4; ++k) {
        local[k] = s;
        int idx = base + k;
        int v = (idx < n) ? cnt[idx] : 0;
        val[k] = v;
        s += v;
    }
    ts[t] = s;
    __syncthreads();
    for (int off = 1; off < THREADS; off <<= 1) {
        int v = ts[t];
        if (t >= off) v += ts[t - off];
        __syncthreads();
        ts[t] = v;
        __syncthreads();
    }
    int excl = (t == 0) ? 0 : ts[t - 1];
    int boff = blk_sums[b];
    #pragma unroll
    for (int k = 0; k < 4; ++k) {
        int idx = base + k;
        if (idx < n) {
            row_off[idx] = boff + excl + local[k];
            norm_in[idx] = rsqrtf((float)max(val[k], 1));
        }
    }
    if (b == 0 && t == 0) row_off[n] = E;
}

// ====== atomic-free CSR fill: csr_src[row_off[dst]+rank] = src ======
__global__ void fill2_kernel(const int* __restrict__ src, const int* __restrict__ dst,
                             const int* __restrict__ rank, const int* __restrict__ row_off,
                             int* __restrict__ csr_src, int E) {
    int t = blockIdx.x * blockDim.x + threadIdx.x;
    int e0 = t * 4;
    if (e0 + 4 <= E) {
        int4 s4 = *(const int4*)(src + e0);
        int4 d4 = *(const int4*)(dst + e0);
        int4 r4 = *(const int4*)(rank + e0);
        csr_src[row_off[d4.x] + r4.x] = s4.x;
        csr_src[row_off[d4.y] + r4.y] = s4.y;
        csr_src[row_off[d4.z] + r4.z] = s4.z;
        csr_src[row_off[d4.w] + r4.w] = s4.w;
    } else if (e0 < E) {
        for (int e = e0; e < E; ++e) csr_src[row_off[dst[e]] + rank[e]] = src[e];
    }
}

// ====== fused W fragment pre-pack (all 3 weights, one dispatch) ======
__device__ __forceinline__ void wpack_one(const float* __restrict__ W, ushort* __restrict__ Wpk,
                                          int OUT, int t) {
    int lane = t & 63, kk = (t >> 6) & 3, ct = t >> 8;
    int col = ct * 16 + (lane & 15);
    int k0 = kk * 32 + (lane >> 4) * 8;
    #pragma unroll
    for (int j = 0; j < 8; ++j)
        Wpk[t * 8 + j] = f2bf(W[(size_t)(k0 + j) * OUT + col]);
}

__global__ void wpack_all(const float* __restrict__ W1, const float* __restrict__ W2,
                          const float* __restrict__ W3, ushort* __restrict__ Wpk1,
                          ushort* __restrict__ Wpk2, ushort* __restrict__ Wpk3) {
    int t = blockIdx.x * blockDim.x + threadIdx.x;
    if (t < 2048)      wpack_one(W1, Wpk1, 128, t);
    else if (t < 4096) wpack_one(W2, Wpk2, 128, t - 2048);
    else if (t < 5120) wpack_one(W3, Wpk3, 64,  t - 4096);
}

// ====== MFMA GEMM: h = bf16((x*norm) @ W), 64 nodes/block ======
template<int OUT, bool IN_F32>
__global__ __launch_bounds__(256) void mfma_gemm(const void* __restrict__ xv,
                                                 const ushort* __restrict__ Wpk,
                                                 const float* __restrict__ norm,
                                                 ushort* __restrict__ h, int n) {
    __shared__ ushort xs[64 * 136];
    const int t = threadIdx.x;
    const int row0 = blockIdx.x * 64;

    if (IN_F32) {
        const float* x = (const float*)xv;
        #pragma unroll
        for (int i = 0; i < 8; ++i) {
            int e = (i * 256 + t) * 4;
            int row = e >> 7, col = e & 127;
            int gr = min(row0 + row, n - 1);
            float nf = norm[gr];
            float4 v = *(const float4*)(x + (size_t)gr * 128 + col);
            ushort4 p;
            p.x = f2bf(v.x * nf); p.y = f2bf(v.y * nf);
            p.z = f2bf(v.z * nf); p.w = f2bf(v.w * nf);
            *(ushort4*)(&xs[row * 136 + col]) = p;
        }
    } else {
        const ushort* x = (const ushort*)xv;
        #pragma unroll
        for (int i = 0; i < 4; ++i) {
            int e = (i * 256 + t) * 8;
            int row = e >> 7, col = e & 127;
            int gr = min(row0 + row, n - 1);
            float nf = norm[gr];
            uint4 v = *(const uint4*)(x + (size_t)gr * 128 + col);
            uint4 o;
            o.x = f2bf(bf_lo(v.x) * nf) | ((uint)f2bf(bf_hi(v.x) * nf) << 16);
            o.y = f2bf(bf_lo(v.y) * nf) | ((uint)f2bf(bf_hi(v.y) * nf) << 16);
            o.z = f2bf(bf_lo(v.z) * nf) | ((uint)f2bf(bf_hi(v.z) * nf) << 16);
            o.w = f2bf(bf_lo(v.w) * nf) | ((uint)f2bf(bf_hi(v.w) * nf) << 16);
            *(uint4*)(&xs[row * 136 + col]) = o;
        }
    }
    __syncthreads();

    const int wave = t >> 6, lane = t & 63;
    const int r = lane & 15, g = lane >> 4;
    const int nrow0 = row0 + wave * 16;

    short8 a[4];
    #pragma unroll
    for (int kk = 0; kk < 4; ++kk)
        a[kk] = *(const short8*)(&xs[(wave * 16 + r) * 136 + kk * 32 + g * 8]);

    const short8* wp = (const short8*)Wpk;
    #pragma unroll
    for (int ct = 0; ct < OUT / 16; ++ct) {
        floatx4 acc = {0.f, 0.f, 0.f, 0.f};
        #pragma unroll
        for (int kk = 0; kk < 4; ++kk) {
            short8 b = wp[(ct * 4 + kk) * 64 + lane];
            acc = __builtin_amdgcn_mfma_f32_16x16x32_bf16(a[kk], b, acc, 0, 0, 0);
        }
        int col = ct * 16 + r;
        #pragma unroll
        for (int rr = 0; rr < 4; ++rr) {
            int grow = nrow0 + g * 4 + rr;
            if (grow < n) h[(size_t)grow * OUT + col] = f2bf(acc[rr]);
        }
    }
}

// ====== CSR aggregation, 128-wide bf16 in, bf16 out ======
template<bool RELU>
__global__ __launch_bounds__(256) void agg128(const ushort* __restrict__ h,
                                              const int* __restrict__ row_off,
                                              const int* __restrict__ csr_src,
                                              const float* __restrict__ nin,
                                              const float* __restrict__ bias,
                                              ushort* __restrict__ out, int n) {
    const int wave = threadIdx.x >> 6;
    const int lane = threadIdx.x & 63;
    const uint* hu = (const uint*)h;
    for (int node = blockIdx.x * 4 + wave; node < n; node += gridDim.x * 4) {
        int beg = row_off[node], end = row_off[node + 1];
        float a0 = 0.f, a1 = 0.f;
        int j = beg;
        for (; j + 3 < end; j += 4) {
            int s0 = csr_src[j], s1 = csr_src[j + 1], s2 = csr_src[j + 2], s3 = csr_src[j + 3];
            uint u0 = hu[(size_t)s0 * 64 + lane];
            uint u1 = hu[(size_t)s1 * 64 + lane];
            uint u2 = hu[(size_t)s2 * 64 + lane];
            uint u3 = hu[(size_t)s3 * 64 + lane];
            a0 += bf_lo(u0); a1 += bf_hi(u0);
            a0 += bf_lo(u1); a1 += bf_hi(u1);
            a0 += bf_lo(u2); a1 += bf_hi(u2);
            a0 += bf_lo(u3); a1 += bf_hi(u3);
        }
        for (; j < end; ++j) {
            uint u = hu[(size_t)csr_src[j] * 64 + lane];
            a0 += bf_lo(u); a1 += bf_hi(u);
        }
        float nf = nin[node];
        float2 bb = *(const float2*)(bias + 2 * lane);
        float r0 = a0 * nf + bb.x;
        float r1 = a1 * nf + bb.y;
        if (RELU) { r0 = fmaxf(r0, 0.f); r1 = fmaxf(r1, 0.f); }
        ((uint*)out)[(size_t)node * 64 + lane] = (uint)f2bf(r0) | ((uint)f2bf(r1) << 16);
    }
}

// ====== CSR aggregation, 64-wide bf16 in, fp32 out (final layer) ======
__global__ __launch_bounds__(256) void agg64_final(const ushort* __restrict__ h,
                                                   const int* __restrict__ row_off,
                                                   const int* __restrict__ csr_src,
                                                   const float* __restrict__ nin,
                                                   const float* __restrict__ bias,
                                                   float* __restrict__ out, int n) {
    const int wave = threadIdx.x >> 6;
    const int lane = threadIdx.x & 63;
    const int half = lane >> 5, u5 = lane & 31;
    const uint* hu = (const uint*)h;
    for (int node = blockIdx.x * 4 + wave; node < n; node += gridDim.x * 4) {
        int beg = row_off[node], end = row_off[node + 1];
        float a0 = 0.f, a1 = 0.f;
        int j = beg + half;
        for (; j + 2 < end; j += 4) {
            int sA = csr_src[j], sB = csr_src[j + 2];
            uint uA = hu[(size_t)sA * 32 + u5];
            uint uB = hu[(size_t)sB * 32 + u5];
            a0 += bf_lo(uA); a1 += bf_hi(uA);
            a0 += bf_lo(uB); a1 += bf_hi(uB);
        }
        if (j < end) {
            uint u = hu[(size_t)csr_src[j] * 32 + u5];
            a0 += bf_lo(u); a1 += bf_hi(u);
        }
        float o0 = a0 + __shfl(a0, u5 + 32);
        float o1 = a1 + __shfl(a1, u5 + 32);
        if (lane < 32) {
            float nf = nin[node];
            float2 bb = *(const float2*)(bias + 2 * u5);
            float2 r;
            r.x = o0 * nf + bb.x;
            r.y = o1 * nf + bb.y;
            *(float2*)(out + (size_t)node * 64 + 2 * u5) = r;
        }
    }
}

extern "C" void kernel_launch(void* const* d_in, const int* in_sizes, int n_in,
                              void* d_out, int out_size, void* d_ws, size_t ws_size,
                              hipStream_t stream) {
    const float* in_feat = (const float*)d_in[0];
    const int*   src     = (const int*)d_in[1];
    const int*   dst     = (const int*)d_in[2];
    const float* W1      = (const float*)d_in[3];
    const float* b1      = (const float*)d_in[4];
    const float* W2      = (const float*)d_in[5];
    const float* b2      = (const float*)d_in[6];
    const float* W3      = (const float*)d_in[7];
    const float* b3      = (const float*)d_in[8];

    const int n = in_sizes[0] / 128;
    const int E = in_sizes[1];
    float* out = (float*)d_out;

    // ws: norm_out[n], norm_in[n] (f32); row_off[n+2], csr_src[E]; Wpk1/2/3; bufA, bufB (ushort)
    float* ws       = (float*)d_ws;
    float* norm_out = ws;
    float* norm_in  = ws + n;
    int*   row_off  = (int*)(ws + 2 * (size_t)n);
    int*   csr_src  = row_off + (n + 2);
    ushort* Wpk1    = (ushort*)(csr_src + E);
    ushort* Wpk2    = Wpk1 + 128 * 128;
    ushort* Wpk3    = Wpk2 + 128 * 128;
    ushort* bufA    = Wpk3 + 128 * 64;
    ushort* bufB    = bufA + (size_t)n * 128;
    // overlays (dead before their region is first written by the main pipeline):
    int* cnt_in   = (int*)bufA;          // dead after scan_phase3 (gemm1 writes bufA later)
    int* blk_sums = cnt_in + n;
    int* rank     = (int*)bufB;          // dead after fill2 (agg128 L1 writes bufB later)

    const int nb = (n + SCAN_BLK - 1) / SCAN_BLK;
    const int k1_grid = HB + (E / 4 + K1_BLK - 1) / K1_BLK;

    // ---- CSR build + norms + W pack ----
    hipMemsetAsync(cnt_in, 0, (size_t)n * sizeof(int), stream);
    wpack_all<<<20, THREADS, 0, stream>>>(W1, W2, W3, Wpk1, Wpk2, Wpk3);
    k1_kernel<<<k1_grid, K1_BLK, 0, stream>>>(src, dst, cnt_in, rank, norm_out, n, E);
    scan_phase1<<<nb, THREADS, 0, stream>>>(cnt_in, blk_sums, n);
    scan_phase2<<<1, 1024, 0, stream>>>(blk_sums, nb);
    scan_phase3<<<nb, THREADS, 0, stream>>>(cnt_in, blk_sums, row_off, norm_in, n, E);
    fill2_kernel<<<(E / 4 + THREADS - 1) / THREADS, THREADS, 0, stream>>>(src, dst, rank, row_off, csr_src, E);

    const int gemm_grid = (n + 63) / 64;
    const int agg_grid  = 4096;

    // ---- layer 1 ----
    mfma_gemm<128, true><<<gemm_grid, THREADS, 0, stream>>>(in_feat, Wpk1, norm_out, bufA, n);
    agg128<true><<<agg_grid, THREADS, 0, stream>>>(bufA, row_off, csr_src, norm_in, b1, bufB, n);
    // ---- layer 2 ----
    mfma_gemm<128, false><<<gemm_grid, THREADS, 0, stream>>>(bufB, Wpk2, norm_out, bufA, n);
    agg128<true><<<agg_grid, THREADS, 0, stream>>>(bufA, row_off, csr_src, norm_in, b2, bufB, n);
    // ---- layer 3 ----
    mfma_gemm<64, false><<<gemm_grid, THREADS, 0, stream>>>(bufB, Wpk3, norm_out, bufA, n);
    agg64_final<<<agg_grid, THREADS, 0, stream>>>(bufA, row_off, csr_src, norm_in, b3, out, n);
}

// Round 5
// 481.037 us; speedup vs baseline: 1.3741x; 1.3741x over previous
//
#include <hip/hip_runtime.h>

#define THREADS 256
#define SCAN_BLK 1024

typedef __attribute__((ext_vector_type(8))) short short8;
typedef __attribute__((ext_vector_type(4))) float floatx4;

__device__ __forceinline__ ushort f2bf(float f) {
    union { float f; uint u; } v; v.f = f;
    uint u = v.u;
    return (ushort)((u + 0x7FFFu + ((u >> 16) & 1u)) >> 16);   // RNE
}
__device__ __forceinline__ float bf_lo(uint u) {
    union { uint u; float f; } v; v.u = u << 16; return v.f;
}
__device__ __forceinline__ float bf_hi(uint u) {
    union { uint u; float f; } v; v.u = u & 0xFFFF0000u; return v.f;
}

// ====== K1: degree counts + dst-rank in one pass (4 edges/thread, 8 atomics in flight) ======
__global__ __launch_bounds__(256) void k1_kernel(const int* __restrict__ src,
                                                 const int* __restrict__ dst,
                                                 int* __restrict__ cnt_out,
                                                 int* __restrict__ cnt_in,
                                                 int* __restrict__ rank, int E) {
    int t = blockIdx.x * blockDim.x + threadIdx.x;
    int e0 = t * 4;
    if (e0 + 4 <= E) {
        int4 s4 = *(const int4*)(src + e0);
        int4 d4 = *(const int4*)(dst + e0);
        atomicAdd(&cnt_out[s4.x], 1);
        atomicAdd(&cnt_out[s4.y], 1);
        atomicAdd(&cnt_out[s4.z], 1);
        atomicAdd(&cnt_out[s4.w], 1);
        int4 r;
        r.x = atomicAdd(&cnt_in[d4.x], 1);
        r.y = atomicAdd(&cnt_in[d4.y], 1);
        r.z = atomicAdd(&cnt_in[d4.z], 1);
        r.w = atomicAdd(&cnt_in[d4.w], 1);
        *(int4*)(rank + e0) = r;
    } else if (e0 < E) {
        for (int e = e0; e < E; ++e) {
            atomicAdd(&cnt_out[src[e]], 1);
            rank[e] = atomicAdd(&cnt_in[dst[e]], 1);
        }
    }
}

// ====== exclusive scan of cnt_in -> row_off; phase3 also emits norm_in AND norm_out ======
__global__ void scan_phase1(const int* __restrict__ cnt, int* __restrict__ blk_sums, int n) {
    int base = blockIdx.x * SCAN_BLK;
    int t = threadIdx.x;
    int sum = 0;
    for (int i = t; i < SCAN_BLK; i += THREADS) {
        int idx = base + i;
        sum += (idx < n) ? cnt[idx] : 0;
    }
    __shared__ int wsum[4];
    for (int off = 32; off > 0; off >>= 1) sum += __shfl_down(sum, off);
    if ((t & 63) == 0) wsum[t >> 6] = sum;
    __syncthreads();
    if (t == 0) blk_sums[blockIdx.x] = wsum[0] + wsum[1] + wsum[2] + wsum[3];
}

__global__ void scan_phase2(int* __restrict__ blk_sums, int nb) {
    __shared__ int s[1024];
    int t = threadIdx.x;
    s[t] = (t < nb) ? blk_sums[t] : 0;
    __syncthreads();
    for (int off = 1; off < 1024; off <<= 1) {
        int v = s[t];
        if (t >= off) v += s[t - off];
        __syncthreads();
        s[t] = v;
        __syncthreads();
    }
    if (t < nb) blk_sums[t] = (t == 0) ? 0 : s[t - 1];
}

__global__ void scan_phase3(const int* __restrict__ cnt, const int* __restrict__ cnt_out,
                            const int* __restrict__ blk_sums,
                            int* __restrict__ row_off, float* __restrict__ norm_in,
                            float* __restrict__ norm_out, int n, int E) {
    __shared__ int ts[THREADS];
    int b = blockIdx.x, t = threadIdx.x;
    int base = b * SCAN_BLK + t * 4;
    int local[4], val[4]; int s = 0;
    #pragma unroll
    for (int k = 0; k < 4; ++k) {
        local[k] = s;
        int idx = base + k;
        int v = (idx < n) ? cnt[idx] : 0;
        val[k] = v;
        s += v;
    }
    ts[t] = s;
    __syncthreads();
    for (int off = 1; off < THREADS; off <<= 1) {
        int v = ts[t];
        if (t >= off) v += ts[t - off];
        __syncthreads();
        ts[t] = v;
        __syncthreads();
    }
    int excl = (t == 0) ? 0 : ts[t - 1];
    int boff = blk_sums[b];
    #pragma unroll
    for (int k = 0; k < 4; ++k) {
        int idx = base + k;
        if (idx < n) {
            row_off[idx] = boff + excl + local[k];
            norm_in[idx]  = rsqrtf((float)max(val[k], 1));
            norm_out[idx] = rsqrtf((float)max(cnt_out[idx], 1));
        }
    }
    if (b == 0 && t == 0) row_off[n] = E;
}

// ====== atomic-free CSR fill: csr_src[row_off[dst]+rank] = src ======
__global__ void fill2_kernel(const int* __restrict__ src, const int* __restrict__ dst,
                             const int* __restrict__ rank, const int* __restrict__ row_off,
                             int* __restrict__ csr_src, int E) {
    int t = blockIdx.x * blockDim.x + threadIdx.x;
    int e0 = t * 4;
    if (e0 + 4 <= E) {
        int4 s4 = *(const int4*)(src + e0);
        int4 d4 = *(const int4*)(dst + e0);
        int4 r4 = *(const int4*)(rank + e0);
        csr_src[row_off[d4.x] + r4.x] = s4.x;
        csr_src[row_off[d4.y] + r4.y] = s4.y;
        csr_src[row_off[d4.z] + r4.z] = s4.z;
        csr_src[row_off[d4.w] + r4.w] = s4.w;
    } else if (e0 < E) {
        for (int e = e0; e < E; ++e) csr_src[row_off[dst[e]] + rank[e]] = src[e];
    }
}

// ====== fused W fragment pre-pack (all 3 weights, one dispatch) ======
__device__ __forceinline__ void wpack_one(const float* __restrict__ W, ushort* __restrict__ Wpk,
                                          int OUT, int t) {
    int lane = t & 63, kk = (t >> 6) & 3, ct = t >> 8;
    int col = ct * 16 + (lane & 15);
    int k0 = kk * 32 + (lane >> 4) * 8;
    #pragma unroll
    for (int j = 0; j < 8; ++j)
        Wpk[t * 8 + j] = f2bf(W[(size_t)(k0 + j) * OUT + col]);
}

__global__ void wpack_all(const float* __restrict__ W1, const float* __restrict__ W2,
                          const float* __restrict__ W3, ushort* __restrict__ Wpk1,
                          ushort* __restrict__ Wpk2, ushort* __restrict__ Wpk3) {
    int t = blockIdx.x * blockDim.x + threadIdx.x;
    if (t < 2048)      wpack_one(W1, Wpk1, 128, t);
    else if (t < 4096) wpack_one(W2, Wpk2, 128, t - 2048);
    else if (t < 5120) wpack_one(W3, Wpk3, 64,  t - 4096);
}

// ====== MFMA GEMM: h = bf16((x*norm) @ W), 64 nodes/block ======
template<int OUT, bool IN_F32>
__global__ __launch_bounds__(256) void mfma_gemm(const void* __restrict__ xv,
                                                 const ushort* __restrict__ Wpk,
                                                 const float* __restrict__ norm,
                                                 ushort* __restrict__ h, int n) {
    __shared__ ushort xs[64 * 136];
    const int t = threadIdx.x;
    const int row0 = blockIdx.x * 64;

    if (IN_F32) {
        const float* x = (const float*)xv;
        #pragma unroll
        for (int i = 0; i < 8; ++i) {
            int e = (i * 256 + t) * 4;
            int row = e >> 7, col = e & 127;
            int gr = min(row0 + row, n - 1);
            float nf = norm[gr];
            float4 v = *(const float4*)(x + (size_t)gr * 128 + col);
            ushort4 p;
            p.x = f2bf(v.x * nf); p.y = f2bf(v.y * nf);
            p.z = f2bf(v.z * nf); p.w = f2bf(v.w * nf);
            *(ushort4*)(&xs[row * 136 + col]) = p;
        }
    } else {
        const ushort* x = (const ushort*)xv;
        #pragma unroll
        for (int i = 0; i < 4; ++i) {
            int e = (i * 256 + t) * 8;
            int row = e >> 7, col = e & 127;
            int gr = min(row0 + row, n - 1);
            float nf = norm[gr];
            uint4 v = *(const uint4*)(x + (size_t)gr * 128 + col);
            uint4 o;
            o.x = f2bf(bf_lo(v.x) * nf) | ((uint)f2bf(bf_hi(v.x) * nf) << 16);
            o.y = f2bf(bf_lo(v.y) * nf) | ((uint)f2bf(bf_hi(v.y) * nf) << 16);
            o.z = f2bf(bf_lo(v.z) * nf) | ((uint)f2bf(bf_hi(v.z) * nf) << 16);
            o.w = f2bf(bf_lo(v.w) * nf) | ((uint)f2bf(bf_hi(v.w) * nf) << 16);
            *(uint4*)(&xs[row * 136 + col]) = o;
        }
    }
    __syncthreads();

    const int wave = t >> 6, lane = t & 63;
    const int r = lane & 15, g = lane >> 4;
    const int nrow0 = row0 + wave * 16;

    short8 a[4];
    #pragma unroll
    for (int kk = 0; kk < 4; ++kk)
        a[kk] = *(const short8*)(&xs[(wave * 16 + r) * 136 + kk * 32 + g * 8]);

    const short8* wp = (const short8*)Wpk;
    #pragma unroll
    for (int ct = 0; ct < OUT / 16; ++ct) {
        floatx4 acc = {0.f, 0.f, 0.f, 0.f};
        #pragma unroll
        for (int kk = 0; kk < 4; ++kk) {
            short8 b = wp[(ct * 4 + kk) * 64 + lane];
            acc = __builtin_amdgcn_mfma_f32_16x16x32_bf16(a[kk], b, acc, 0, 0, 0);
        }
        int col = ct * 16 + r;
        #pragma unroll
        for (int rr = 0; rr < 4; ++rr) {
            int grow = nrow0 + g * 4 + rr;
            if (grow < n) h[(size_t)grow * OUT + col] = f2bf(acc[rr]);
        }
    }
}

// ====== CSR aggregation, 128-wide bf16 in, bf16 out ======
template<bool RELU>
__global__ __launch_bounds__(256) void agg128(const ushort* __restrict__ h,
                                              const int* __restrict__ row_off,
                                              const int* __restrict__ csr_src,
                                              const float* __restrict__ nin,
                                              const float* __restrict__ bias,
                                              ushort* __restrict__ out, int n) {
    const int wave = threadIdx.x >> 6;
    const int lane = threadIdx.x & 63;
    const uint* hu = (const uint*)h;
    for (int node = blockIdx.x * 4 + wave; node < n; node += gridDim.x * 4) {
        int beg = row_off[node], end = row_off[node + 1];
        float a0 = 0.f, a1 = 0.f;
        int j = beg;
        for (; j + 3 < end; j += 4) {
            int s0 = csr_src[j], s1 = csr_src[j + 1], s2 = csr_src[j + 2], s3 = csr_src[j + 3];
            uint u0 = hu[(size_t)s0 * 64 + lane];
            uint u1 = hu[(size_t)s1 * 64 + lane];
            uint u2 = hu[(size_t)s2 * 64 + lane];
            uint u3 = hu[(size_t)s3 * 64 + lane];
            a0 += bf_lo(u0); a1 += bf_hi(u0);
            a0 += bf_lo(u1); a1 += bf_hi(u1);
            a0 += bf_lo(u2); a1 += bf_hi(u2);
            a0 += bf_lo(u3); a1 += bf_hi(u3);
        }
        for (; j < end; ++j) {
            uint u = hu[(size_t)csr_src[j] * 64 + lane];
            a0 += bf_lo(u); a1 += bf_hi(u);
        }
        float nf = nin[node];
        float2 bb = *(const float2*)(bias + 2 * lane);
        float r0 = a0 * nf + bb.x;
        float r1 = a1 * nf + bb.y;
        if (RELU) { r0 = fmaxf(r0, 0.f); r1 = fmaxf(r1, 0.f); }
        ((uint*)out)[(size_t)node * 64 + lane] = (uint)f2bf(r0) | ((uint)f2bf(r1) << 16);
    }
}

// ====== CSR aggregation, 64-wide bf16 in, fp32 out (final layer) ======
__global__ __launch_bounds__(256) void agg64_final(const ushort* __restrict__ h,
                                                   const int* __restrict__ row_off,
                                                   const int* __restrict__ csr_src,
                                                   const float* __restrict__ nin,
                                                   const float* __restrict__ bias,
                                                   float* __restrict__ out, int n) {
    const int wave = threadIdx.x >> 6;
    const int lane = threadIdx.x & 63;
    const int half = lane >> 5, u5 = lane & 31;
    const uint* hu = (const uint*)h;
    for (int node = blockIdx.x * 4 + wave; node < n; node += gridDim.x * 4) {
        int beg = row_off[node], end = row_off[node + 1];
        float a0 = 0.f, a1 = 0.f;
        int j = beg + half;
        for (; j + 2 < end; j += 4) {
            int sA = csr_src[j], sB = csr_src[j + 2];
            uint uA = hu[(size_t)sA * 32 + u5];
            uint uB = hu[(size_t)sB * 32 + u5];
            a0 += bf_lo(uA); a1 += bf_hi(uA);
            a0 += bf_lo(uB); a1 += bf_hi(uB);
        }
        if (j < end) {
            uint u = hu[(size_t)csr_src[j] * 32 + u5];
            a0 += bf_lo(u); a1 += bf_hi(u);
        }
        float o0 = a0 + __shfl(a0, u5 + 32);
        float o1 = a1 + __shfl(a1, u5 + 32);
        if (lane < 32) {
            float nf = nin[node];
            float2 bb = *(const float2*)(bias + 2 * u5);
            float2 r;
            r.x = o0 * nf + bb.x;
            r.y = o1 * nf + bb.y;
            *(float2*)(out + (size_t)node * 64 + 2 * u5) = r;
        }
    }
}

extern "C" void kernel_launch(void* const* d_in, const int* in_sizes, int n_in,
                              void* d_out, int out_size, void* d_ws, size_t ws_size,
                              hipStream_t stream) {
    const float* in_feat = (const float*)d_in[0];
    const int*   src     = (const int*)d_in[1];
    const int*   dst     = (const int*)d_in[2];
    const float* W1      = (const float*)d_in[3];
    const float* b1      = (const float*)d_in[4];
    const float* W2      = (const float*)d_in[5];
    const float* b2      = (const float*)d_in[6];
    const float* W3      = (const float*)d_in[7];
    const float* b3      = (const float*)d_in[8];

    const int n = in_sizes[0] / 128;
    const int E = in_sizes[1];
    float* out = (float*)d_out;

    // ws: norm_out[n], norm_in[n] (f32); row_off[n+2], csr_src[E]; Wpk1/2/3; bufA, bufB (ushort)
    float* ws       = (float*)d_ws;
    float* norm_out = ws;
    float* norm_in  = ws + n;
    int*   row_off  = (int*)(ws + 2 * (size_t)n);
    int*   csr_src  = row_off + (n + 2);
    ushort* Wpk1    = (ushort*)(csr_src + E);
    ushort* Wpk2    = Wpk1 + 128 * 128;
    ushort* Wpk3    = Wpk2 + 128 * 128;
    ushort* bufA    = Wpk3 + 128 * 64;
    ushort* bufB    = bufA + (size_t)n * 128;
    // overlays (dead before their region is first written by the main pipeline):
    int* cnt_in   = (int*)bufA;          // dead after scan_phase3 (gemm1 writes bufA later)
    int* cnt_out  = cnt_in + n;
    int* blk_sums = cnt_out + n;
    int* rank     = (int*)bufB;          // dead after fill2 (agg128 L1 writes bufB later)

    const int nb = (n + SCAN_BLK - 1) / SCAN_BLK;

    // ---- CSR build + norms + W pack ----
    hipMemsetAsync(cnt_in, 0, 2 * (size_t)n * sizeof(int), stream);
    wpack_all<<<20, THREADS, 0, stream>>>(W1, W2, W3, Wpk1, Wpk2, Wpk3);
    k1_kernel<<<(E / 4 + THREADS - 1) / THREADS, THREADS, 0, stream>>>(src, dst, cnt_out, cnt_in, rank, E);
    scan_phase1<<<nb, THREADS, 0, stream>>>(cnt_in, blk_sums, n);
    scan_phase2<<<1, 1024, 0, stream>>>(blk_sums, nb);
    scan_phase3<<<nb, THREADS, 0, stream>>>(cnt_in, cnt_out, blk_sums, row_off, norm_in, norm_out, n, E);
    fill2_kernel<<<(E / 4 + THREADS - 1) / THREADS, THREADS, 0, stream>>>(src, dst, rank, row_off, csr_src, E);

    const int gemm_grid = (n + 63) / 64;
    const int agg_grid  = 4096;

    // ---- layer 1 ----
    mfma_gemm<128, true><<<gemm_grid, THREADS, 0, stream>>>(in_feat, Wpk1, norm_out, bufA, n);
    agg128<true><<<agg_grid, THREADS, 0, stream>>>(bufA, row_off, csr_src, norm_in, b1, bufB, n);
    // ---- layer 2 ----
    mfma_gemm<128, false><<<gemm_grid, THREADS, 0, stream>>>(bufB, Wpk2, norm_out, bufA, n);
    agg128<true><<<agg_grid, THREADS, 0, stream>>>(bufA, row_off, csr_src, norm_in, b2, bufB, n);
    // ---- layer 3 ----
    mfma_gemm<64, false><<<gemm_grid, THREADS, 0, stream>>>(bufB, Wpk3, norm_out, bufA, n);
    agg64_final<<<agg_grid, THREADS, 0, stream>>>(bufA, row_off, csr_src, norm_in, b3, out, n);
}

// Round 6
// 433.541 us; speedup vs baseline: 1.5247x; 1.1096x over previous
//
#include <hip/hip_runtime.h>

#define THREADS 256
#define SCAN_BLK 1024
#define NR 8            // histogram node ranges
#define NC 32           // histogram edge chunks

typedef __attribute__((ext_vector_type(8))) short short8;
typedef __attribute__((ext_vector_type(4))) float floatx4;

__device__ __forceinline__ ushort f2bf(float f) {
    union { float f; uint u; } v; v.f = f;
    uint u = v.u;
    return (ushort)((u + 0x7FFFu + ((u >> 16) & 1u)) >> 16);   // RNE
}
__device__ __forceinline__ float bf_lo(uint u) {
    union { uint u; float f; } v; v.u = u << 16; return v.f;
}
__device__ __forceinline__ float bf_hi(uint u) {
    union { uint u; float f; } v; v.u = u & 0xFFFF0000u; return v.f;
}

// ====== K1 (slim): dst rank only: rank[e] = atomicAdd(cnt_in[dst[e]], 1) ======
__global__ __launch_bounds__(256) void k1_kernel(const int* __restrict__ dst,
                                                 int* __restrict__ cnt_in,
                                                 int* __restrict__ rank, int E) {
    int t = blockIdx.x * blockDim.x + threadIdx.x;
    int e0 = t * 4;
    if (e0 + 4 <= E) {
        int4 d4 = *(const int4*)(dst + e0);
        int4 r;
        r.x = atomicAdd(&cnt_in[d4.x], 1);
        r.y = atomicAdd(&cnt_in[d4.y], 1);
        r.z = atomicAdd(&cnt_in[d4.z], 1);
        r.w = atomicAdd(&cnt_in[d4.w], 1);
        *(int4*)(rank + e0) = r;
    } else if (e0 < E) {
        for (int e = e0; e < E; ++e) rank[e] = atomicAdd(&cnt_in[dst[e]], 1);
    }
}

// ====== src out-degree histogram: NR ranges x NC chunks, LDS counts, coalesced merge ======
__global__ __launch_bounds__(256) void hist_out_kernel(const int* __restrict__ src,
                                                       int* __restrict__ cnt_out,
                                                       int n, int E) {
    __shared__ uint cnt[12544];                      // ceil(100000/8)=12500
    const int range = blockIdx.x / NC;
    const int chunk = blockIdx.x % NC;
    const int Rsz = (n + NR - 1) / NR;
    const int lo  = range * Rsz;
    const int R   = min(n - lo, Rsz);
    if (R <= 0) return;
    for (int i = threadIdx.x; i < R; i += THREADS) cnt[i] = 0;
    __syncthreads();

    // edge chunk [c0, c1)
    const int per = (E + NC - 1) / NC;
    const int c0 = chunk * per;
    const int c1 = min(E, c0 + per);
    int i = c0 + threadIdx.x * 4;
    for (; i + 4 <= c1; i += THREADS * 4) {
        int4 v = *(const int4*)(src + i);
        if ((unsigned)(v.x - lo) < (unsigned)R) atomicAdd(&cnt[v.x - lo], 1u);
        if ((unsigned)(v.y - lo) < (unsigned)R) atomicAdd(&cnt[v.y - lo], 1u);
        if ((unsigned)(v.z - lo) < (unsigned)R) atomicAdd(&cnt[v.z - lo], 1u);
        if ((unsigned)(v.w - lo) < (unsigned)R) atomicAdd(&cnt[v.w - lo], 1u);
    }
    for (; i < c1; ++i) {
        int s = src[i];
        if ((unsigned)(s - lo) < (unsigned)R) atomicAdd(&cnt[s - lo], 1u);
    }
    __syncthreads();
    // coalesced merge
    for (int k = threadIdx.x; k < R; k += THREADS) {
        uint c = cnt[k];
        if (c) atomicAdd(&cnt_out[lo + k], (int)c);
    }
}

// ====== exclusive scan of cnt_in -> row_off; phase3 also emits norm_in AND norm_out ======
__global__ void scan_phase1(const int* __restrict__ cnt, int* __restrict__ blk_sums, int n) {
    int base = blockIdx.x * SCAN_BLK;
    int t = threadIdx.x;
    int sum = 0;
    for (int i = t; i < SCAN_BLK; i += THREADS) {
        int idx = base + i;
        sum += (idx < n) ? cnt[idx] : 0;
    }
    __shared__ int wsum[4];
    for (int off = 32; off > 0; off >>= 1) sum += __shfl_down(sum, off);
    if ((t & 63) == 0) wsum[t >> 6] = sum;
    __syncthreads();
    if (t == 0) blk_sums[blockIdx.x] = wsum[0] + wsum[1] + wsum[2] + wsum[3];
}

__global__ void scan_phase2(int* __restrict__ blk_sums, int nb) {
    __shared__ int s[1024];
    int t = threadIdx.x;
    s[t] = (t < nb) ? blk_sums[t] : 0;
    __syncthreads();
    for (int off = 1; off < 1024; off <<= 1) {
        int v = s[t];
        if (t >= off) v += s[t - off];
        __syncthreads();
        s[t] = v;
        __syncthreads();
    }
    if (t < nb) blk_sums[t] = (t == 0) ? 0 : s[t - 1];
}

__global__ void scan_phase3(const int* __restrict__ cnt, const int* __restrict__ cnt_out,
                            const int* __restrict__ blk_sums,
                            int* __restrict__ row_off, float* __restrict__ norm_in,
                            float* __restrict__ norm_out, int n, int E) {
    __shared__ int ts[THREADS];
    int b = blockIdx.x, t = threadIdx.x;
    int base = b * SCAN_BLK + t * 4;
    int local[4], val[4]; int s = 0;
    #pragma unroll
    for (int k = 0; k < 4; ++k) {
        local[k] = s;
        int idx = base + k;
        int v = (idx < n) ? cnt[idx] : 0;
        val[k] = v;
        s += v;
    }
    ts[t] = s;
    __syncthreads();
    for (int off = 1; off < THREADS; off <<= 1) {
        int v = ts[t];
        if (t >= off) v += ts[t - off];
        __syncthreads();
        ts[t] = v;
        __syncthreads();
    }
    int excl = (t == 0) ? 0 : ts[t - 1];
    int boff = blk_sums[b];
    #pragma unroll
    for (int k = 0; k < 4; ++k) {
        int idx = base + k;
        if (idx < n) {
            row_off[idx] = boff + excl + local[k];
            norm_in[idx]  = rsqrtf((float)max(val[k], 1));
            norm_out[idx] = rsqrtf((float)max(cnt_out[idx], 1));
        }
    }
    if (b == 0 && t == 0) row_off[n] = E;
}

// ====== atomic-free CSR fill: csr_src[row_off[dst]+rank] = src ======
__global__ void fill2_kernel(const int* __restrict__ src, const int* __restrict__ dst,
                             const int* __restrict__ rank, const int* __restrict__ row_off,
                             int* __restrict__ csr_src, int E) {
    int t = blockIdx.x * blockDim.x + threadIdx.x;
    int e0 = t * 4;
    if (e0 + 4 <= E) {
        int4 s4 = *(const int4*)(src + e0);
        int4 d4 = *(const int4*)(dst + e0);
        int4 r4 = *(const int4*)(rank + e0);
        csr_src[row_off[d4.x] + r4.x] = s4.x;
        csr_src[row_off[d4.y] + r4.y] = s4.y;
        csr_src[row_off[d4.z] + r4.z] = s4.z;
        csr_src[row_off[d4.w] + r4.w] = s4.w;
    } else if (e0 < E) {
        for (int e = e0; e < E; ++e) csr_src[row_off[dst[e]] + rank[e]] = src[e];
    }
}

// ====== fused W fragment pre-pack (all 3 weights, one dispatch) ======
__device__ __forceinline__ void wpack_one(const float* __restrict__ W, ushort* __restrict__ Wpk,
                                          int OUT, int t) {
    int lane = t & 63, kk = (t >> 6) & 3, ct = t >> 8;
    int col = ct * 16 + (lane & 15);
    int k0 = kk * 32 + (lane >> 4) * 8;
    #pragma unroll
    for (int j = 0; j < 8; ++j)
        Wpk[t * 8 + j] = f2bf(W[(size_t)(k0 + j) * OUT + col]);
}

__global__ void wpack_all(const float* __restrict__ W1, const float* __restrict__ W2,
                          const float* __restrict__ W3, ushort* __restrict__ Wpk1,
                          ushort* __restrict__ Wpk2, ushort* __restrict__ Wpk3) {
    int t = blockIdx.x * blockDim.x + threadIdx.x;
    if (t < 2048)      wpack_one(W1, Wpk1, 128, t);
    else if (t < 4096) wpack_one(W2, Wpk2, 128, t - 2048);
    else if (t < 5120) wpack_one(W3, Wpk3, 64,  t - 4096);
}

// ====== MFMA GEMM: h = bf16((x*norm) @ W), 64 nodes/block ======
template<int OUT, bool IN_F32>
__global__ __launch_bounds__(256) void mfma_gemm(const void* __restrict__ xv,
                                                 const ushort* __restrict__ Wpk,
                                                 const float* __restrict__ norm,
                                                 ushort* __restrict__ h, int n) {
    __shared__ ushort xs[64 * 136];
    const int t = threadIdx.x;
    const int row0 = blockIdx.x * 64;

    if (IN_F32) {
        const float* x = (const float*)xv;
        #pragma unroll
        for (int i = 0; i < 8; ++i) {
            int e = (i * 256 + t) * 4;
            int row = e >> 7, col = e & 127;
            int gr = min(row0 + row, n - 1);
            float nf = norm[gr];
            float4 v = *(const float4*)(x + (size_t)gr * 128 + col);
            ushort4 p;
            p.x = f2bf(v.x * nf); p.y = f2bf(v.y * nf);
            p.z = f2bf(v.z * nf); p.w = f2bf(v.w * nf);
            *(ushort4*)(&xs[row * 136 + col]) = p;
        }
    } else {
        const ushort* x = (const ushort*)xv;
        #pragma unroll
        for (int i = 0; i < 4; ++i) {
            int e = (i * 256 + t) * 8;
            int row = e >> 7, col = e & 127;
            int gr = min(row0 + row, n - 1);
            float nf = norm[gr];
            uint4 v = *(const uint4*)(x + (size_t)gr * 128 + col);
            uint4 o;
            o.x = f2bf(bf_lo(v.x) * nf) | ((uint)f2bf(bf_hi(v.x) * nf) << 16);
            o.y = f2bf(bf_lo(v.y) * nf) | ((uint)f2bf(bf_hi(v.y) * nf) << 16);
            o.z = f2bf(bf_lo(v.z) * nf) | ((uint)f2bf(bf_hi(v.z) * nf) << 16);
            o.w = f2bf(bf_lo(v.w) * nf) | ((uint)f2bf(bf_hi(v.w) * nf) << 16);
            *(uint4*)(&xs[row * 136 + col]) = o;
        }
    }
    __syncthreads();

    const int wave = t >> 6, lane = t & 63;
    const int r = lane & 15, g = lane >> 4;
    const int nrow0 = row0 + wave * 16;

    short8 a[4];
    #pragma unroll
    for (int kk = 0; kk < 4; ++kk)
        a[kk] = *(const short8*)(&xs[(wave * 16 + r) * 136 + kk * 32 + g * 8]);

    const short8* wp = (const short8*)Wpk;
    #pragma unroll
    for (int ct = 0; ct < OUT / 16; ++ct) {
        floatx4 acc = {0.f, 0.f, 0.f, 0.f};
        #pragma unroll
        for (int kk = 0; kk < 4; ++kk) {
            short8 b = wp[(ct * 4 + kk) * 64 + lane];
            acc = __builtin_amdgcn_mfma_f32_16x16x32_bf16(a[kk], b, acc, 0, 0, 0);
        }
        int col = ct * 16 + r;
        #pragma unroll
        for (int rr = 0; rr < 4; ++rr) {
            int grow = nrow0 + g * 4 + rr;
            if (grow < n) h[(size_t)grow * OUT + col] = f2bf(acc[rr]);
        }
    }
}

// ====== CSR aggregation, 128-wide bf16 in, bf16 out ======
template<bool RELU>
__global__ __launch_bounds__(256) void agg128(const ushort* __restrict__ h,
                                              const int* __restrict__ row_off,
                                              const int* __restrict__ csr_src,
                                              const float* __restrict__ nin,
                                              const float* __restrict__ bias,
                                              ushort* __restrict__ out, int n) {
    const int wave = threadIdx.x >> 6;
    const int lane = threadIdx.x & 63;
    const uint* hu = (const uint*)h;
    for (int node = blockIdx.x * 4 + wave; node < n; node += gridDim.x * 4) {
        int beg = row_off[node], end = row_off[node + 1];
        float a0 = 0.f, a1 = 0.f;
        int j = beg;
        for (; j + 3 < end; j += 4) {
            int s0 = csr_src[j], s1 = csr_src[j + 1], s2 = csr_src[j + 2], s3 = csr_src[j + 3];
            uint u0 = hu[(size_t)s0 * 64 + lane];
            uint u1 = hu[(size_t)s1 * 64 + lane];
            uint u2 = hu[(size_t)s2 * 64 + lane];
            uint u3 = hu[(size_t)s3 * 64 + lane];
            a0 += bf_lo(u0); a1 += bf_hi(u0);
            a0 += bf_lo(u1); a1 += bf_hi(u1);
            a0 += bf_lo(u2); a1 += bf_hi(u2);
            a0 += bf_lo(u3); a1 += bf_hi(u3);
        }
        for (; j < end; ++j) {
            uint u = hu[(size_t)csr_src[j] * 64 + lane];
            a0 += bf_lo(u); a1 += bf_hi(u);
        }
        float nf = nin[node];
        float2 bb = *(const float2*)(bias + 2 * lane);
        float r0 = a0 * nf + bb.x;
        float r1 = a1 * nf + bb.y;
        if (RELU) { r0 = fmaxf(r0, 0.f); r1 = fmaxf(r1, 0.f); }
        ((uint*)out)[(size_t)node * 64 + lane] = (uint)f2bf(r0) | ((uint)f2bf(r1) << 16);
    }
}

// ====== CSR aggregation, 64-wide bf16 in, fp32 out (final layer) ======
__global__ __launch_bounds__(256) void agg64_final(const ushort* __restrict__ h,
                                                   const int* __restrict__ row_off,
                                                   const int* __restrict__ csr_src,
                                                   const float* __restrict__ nin,
                                                   const float* __restrict__ bias,
                                                   float* __restrict__ out, int n) {
    const int wave = threadIdx.x >> 6;
    const int lane = threadIdx.x & 63;
    const int half = lane >> 5, u5 = lane & 31;
    const uint* hu = (const uint*)h;
    for (int node = blockIdx.x * 4 + wave; node < n; node += gridDim.x * 4) {
        int beg = row_off[node], end = row_off[node + 1];
        float a0 = 0.f, a1 = 0.f;
        int j = beg + half;
        for (; j + 2 < end; j += 4) {
            int sA = csr_src[j], sB = csr_src[j + 2];
            uint uA = hu[(size_t)sA * 32 + u5];
            uint uB = hu[(size_t)sB * 32 + u5];
            a0 += bf_lo(uA); a1 += bf_hi(uA);
            a0 += bf_lo(uB); a1 += bf_hi(uB);
        }
        if (j < end) {
            uint u = hu[(size_t)csr_src[j] * 32 + u5];
            a0 += bf_lo(u); a1 += bf_hi(u);
        }
        float o0 = a0 + __shfl(a0, u5 + 32);
        float o1 = a1 + __shfl(a1, u5 + 32);
        if (lane < 32) {
            float nf = nin[node];
            float2 bb = *(const float2*)(bias + 2 * u5);
            float2 r;
            r.x = o0 * nf + bb.x;
            r.y = o1 * nf + bb.y;
            *(float2*)(out + (size_t)node * 64 + 2 * u5) = r;
        }
    }
}

extern "C" void kernel_launch(void* const* d_in, const int* in_sizes, int n_in,
                              void* d_out, int out_size, void* d_ws, size_t ws_size,
                              hipStream_t stream) {
    const float* in_feat = (const float*)d_in[0];
    const int*   src     = (const int*)d_in[1];
    const int*   dst     = (const int*)d_in[2];
    const float* W1      = (const float*)d_in[3];
    const float* b1      = (const float*)d_in[4];
    const float* W2      = (const float*)d_in[5];
    const float* b2      = (const float*)d_in[6];
    const float* W3      = (const float*)d_in[7];
    const float* b3      = (const float*)d_in[8];

    const int n = in_sizes[0] / 128;
    const int E = in_sizes[1];
    float* out = (float*)d_out;

    // ws: norm_out[n], norm_in[n] (f32); row_off[n+2], csr_src[E]; Wpk1/2/3; bufA, bufB (ushort)
    float* ws       = (float*)d_ws;
    float* norm_out = ws;
    float* norm_in  = ws + n;
    int*   row_off  = (int*)(ws + 2 * (size_t)n);
    int*   csr_src  = row_off + (n + 2);
    ushort* Wpk1    = (ushort*)(csr_src + E);
    ushort* Wpk2    = Wpk1 + 128 * 128;
    ushort* Wpk3    = Wpk2 + 128 * 128;
    ushort* bufA    = Wpk3 + 128 * 64;
    ushort* bufB    = bufA + (size_t)n * 128;
    // overlays (dead before their region is first written by the main pipeline):
    int* cnt_in   = (int*)bufA;          // dead after scan_phase3 (gemm1 writes bufA later)
    int* cnt_out  = cnt_in + n;
    int* blk_sums = cnt_out + n;
    int* rank     = (int*)bufB;          // dead after fill2 (agg128 L1 writes bufB later)

    const int nb = (n + SCAN_BLK - 1) / SCAN_BLK;

    // ---- CSR build + norms + W pack ----
    hipMemsetAsync(cnt_in, 0, 2 * (size_t)n * sizeof(int), stream);
    wpack_all<<<20, THREADS, 0, stream>>>(W1, W2, W3, Wpk1, Wpk2, Wpk3);
    k1_kernel<<<(E / 4 + THREADS - 1) / THREADS, THREADS, 0, stream>>>(dst, cnt_in, rank, E);
    hist_out_kernel<<<NR * NC, THREADS, 0, stream>>>(src, cnt_out, n, E);
    scan_phase1<<<nb, THREADS, 0, stream>>>(cnt_in, blk_sums, n);
    scan_phase2<<<1, 1024, 0, stream>>>(blk_sums, nb);
    scan_phase3<<<nb, THREADS, 0, stream>>>(cnt_in, cnt_out, blk_sums, row_off, norm_in, norm_out, n, E);
    fill2_kernel<<<(E / 4 + THREADS - 1) / THREADS, THREADS, 0, stream>>>(src, dst, rank, row_off, csr_src, E);

    const int gemm_grid = (n + 63) / 64;
    const int agg_grid  = 4096;

    // ---- layer 1 ----
    mfma_gemm<128, true><<<gemm_grid, THREADS, 0, stream>>>(in_feat, Wpk1, norm_out, bufA, n);
    agg128<true><<<agg_grid, THREADS, 0, stream>>>(bufA, row_off, csr_src, norm_in, b1, bufB, n);
    // ---- layer 2 ----
    mfma_gemm<128, false><<<gemm_grid, THREADS, 0, stream>>>(bufB, Wpk2, norm_out, bufA, n);
    agg128<true><<<agg_grid, THREADS, 0, stream>>>(bufA, row_off, csr_src, norm_in, b2, bufB, n);
    // ---- layer 3 ----
    mfma_gemm<64, false><<<gemm_grid, THREADS, 0, stream>>>(bufB, Wpk3, norm_out, bufA, n);
    agg64_final<<<agg_grid, THREADS, 0, stream>>>(bufA, row_off, csr_src, norm_in, b3, out, n);
}

// Round 8
// 417.426 us; speedup vs baseline: 1.5835x; 1.0386x over previous
//
#include <hip/hip_runtime.h>

#define THREADS 256
#define SCAN_BLK 1024
#define NR 8            // node ranges (counting sort + hist)
#define NC 32           // edge chunks
#define RSTRIDE 12544   // padded per-range node stride (>= ceil(100000/8))

typedef __attribute__((ext_vector_type(8))) short short8;
typedef __attribute__((ext_vector_type(4))) float floatx4;

__device__ __forceinline__ ushort f2bf(float f) {
    union { float f; uint u; } v; v.f = f;
    uint u = v.u;
    return (ushort)((u + 0x7FFFu + ((u >> 16) & 1u)) >> 16);   // RNE
}
__device__ __forceinline__ float bf_lo(uint u) {
    union { uint u; float f; } v; v.u = u << 16; return v.f;
}
__device__ __forceinline__ float bf_hi(uint u) {
    union { uint u; float f; } v; v.u = u & 0xFFFF0000u; return v.f;
}

// ====== src out-degree histogram: NR ranges x NC chunks, LDS counts, coalesced merge ======
__global__ __launch_bounds__(256) void hist_out_kernel(const int* __restrict__ src,
                                                       int* __restrict__ cnt_out,
                                                       int n, int E) {
    __shared__ uint cnt[RSTRIDE];
    const int range = blockIdx.x % NR;         // c-major: co-resident blocks share chunk
    const int chunk = blockIdx.x / NR;
    const int Rsz = (n + NR - 1) / NR;
    const int lo  = range * Rsz;
    const int R   = min(n - lo, Rsz);
    if (R <= 0) return;
    for (int i = threadIdx.x; i < R; i += THREADS) cnt[i] = 0;
    __syncthreads();
    const int per = (E + NC - 1) / NC;
    const int c0 = chunk * per;
    const int c1 = min(E, c0 + per);
    int i = c0 + threadIdx.x * 4;
    for (; i + 4 <= c1; i += THREADS * 4) {
        int4 v = *(const int4*)(src + i);
        if ((unsigned)(v.x - lo) < (unsigned)R) atomicAdd(&cnt[v.x - lo], 1u);
        if ((unsigned)(v.y - lo) < (unsigned)R) atomicAdd(&cnt[v.y - lo], 1u);
        if ((unsigned)(v.z - lo) < (unsigned)R) atomicAdd(&cnt[v.z - lo], 1u);
        if ((unsigned)(v.w - lo) < (unsigned)R) atomicAdd(&cnt[v.w - lo], 1u);
    }
    if (i < c1) {
        for (int e = i; e < c1 && e < i + 4; ++e) {
            int s = src[e];
            if ((unsigned)(s - lo) < (unsigned)R) atomicAdd(&cnt[s - lo], 1u);
        }
    }
    __syncthreads();
    for (int k = threadIdx.x; k < R; k += THREADS) {
        uint c = cnt[k];
        if (c) atomicAdd(&cnt_out[lo + k], (int)c);
    }
}

// ====== counting-sort phase A: per-(range,chunk) dst histogram -> PC (ushort) ======
// LDS counters packed 2 nodes/uint (per-chunk count < 65536 so no cross-half carry).
__global__ __launch_bounds__(256) void csr_phaseA(const int* __restrict__ dst,
                                                  ushort* __restrict__ PC, int n, int E) {
    __shared__ uint cnt[RSTRIDE / 2];
    const int range = blockIdx.x % NR;
    const int chunk = blockIdx.x / NR;
    const int Rsz = (n + NR - 1) / NR;
    const int lo  = range * Rsz;
    const int R   = min(n - lo, Rsz);
    if (R <= 0) return;
    const int Rp = (R + 2) >> 1;
    for (int i = threadIdx.x; i < Rp; i += THREADS) cnt[i] = 0;
    __syncthreads();
    const int per = (E + NC - 1) / NC;
    const int c0 = chunk * per;
    const int c1 = min(E, c0 + per);
    int i = c0 + threadIdx.x * 4;
    for (; i + 4 <= c1; i += THREADS * 4) {
        int4 v = *(const int4*)(dst + i);
        int kx = v.x - lo, ky = v.y - lo, kz = v.z - lo, kw = v.w - lo;
        if ((unsigned)kx < (unsigned)R) atomicAdd(&cnt[kx >> 1], (kx & 1) ? 65536u : 1u);
        if ((unsigned)ky < (unsigned)R) atomicAdd(&cnt[ky >> 1], (ky & 1) ? 65536u : 1u);
        if ((unsigned)kz < (unsigned)R) atomicAdd(&cnt[kz >> 1], (kz & 1) ? 65536u : 1u);
        if ((unsigned)kw < (unsigned)R) atomicAdd(&cnt[kw >> 1], (kw & 1) ? 65536u : 1u);
    }
    if (i < c1) {
        for (int e = i; e < c1 && e < i + 4; ++e) {
            int k = dst[e] - lo;
            if ((unsigned)k < (unsigned)R) atomicAdd(&cnt[k >> 1], (k & 1) ? 65536u : 1u);
        }
    }
    __syncthreads();
    ushort* pc = PC + (size_t)(range * NC + chunk) * RSTRIDE;
    for (int k = threadIdx.x; k < R; k += THREADS) {
        uint c = cnt[k >> 1];
        pc[k] = (ushort)((k & 1) ? (c >> 16) : (c & 0xFFFFu));
    }
}

// ====== colsum: cnt_in[node] = sum over chunks of PC ======
__global__ void csr_colsum(const ushort* __restrict__ PC, int* __restrict__ cnt_in, int n) {
    int gk = blockIdx.x * blockDim.x + threadIdx.x;
    if (gk >= n) return;
    const int Rsz = (n + NR - 1) / NR;
    int r = gk / Rsz, k = gk - r * Rsz;
    int t = 0;
    #pragma unroll 4
    for (int c = 0; c < NC; ++c)
        t += PC[(size_t)(r * NC + c) * RSTRIDE + k];
    cnt_in[gk] = t;
}

// ====== mkbase: B[r][c][k] = row_off[node] + prefix_{c'<c} PC ======
__global__ void csr_mkbase(const ushort* __restrict__ PC, const int* __restrict__ row_off,
                           int* __restrict__ B, int n) {
    int gk = blockIdx.x * blockDim.x + threadIdx.x;
    if (gk >= n) return;
    const int Rsz = (n + NR - 1) / NR;
    int r = gk / Rsz, k = gk - r * Rsz;
    int base = row_off[gk];
    for (int c = 0; c < NC; ++c) {
        size_t idx = (size_t)(r * NC + c) * RSTRIDE + k;
        B[idx] = base;
        base += PC[idx];
    }
}

// ====== counting-sort phase C: LDS cursors, scatter csr_src (no global atomics) ======
__global__ __launch_bounds__(256) void csr_phaseC(const int* __restrict__ src,
                                                  const int* __restrict__ dst,
                                                  const int* __restrict__ B,
                                                  int* __restrict__ csr_src, int n, int E) {
    __shared__ int cur[RSTRIDE];
    const int range = blockIdx.x % NR;
    const int chunk = blockIdx.x / NR;
    const int Rsz = (n + NR - 1) / NR;
    const int lo  = range * Rsz;
    const int R   = min(n - lo, Rsz);
    if (R <= 0) return;
    const int* b = B + (size_t)(range * NC + chunk) * RSTRIDE;
    for (int i = threadIdx.x; i < R; i += THREADS) cur[i] = b[i];
    __syncthreads();
    const int per = (E + NC - 1) / NC;
    const int c0 = chunk * per;
    const int c1 = min(E, c0 + per);
    int i = c0 + threadIdx.x * 4;
    for (; i + 4 <= c1; i += THREADS * 4) {
        int4 d = *(const int4*)(dst + i);
        int4 s = *(const int4*)(src + i);
        int kx = d.x - lo, ky = d.y - lo, kz = d.z - lo, kw = d.w - lo;
        if ((unsigned)kx < (unsigned)R) csr_src[atomicAdd(&cur[kx], 1)] = s.x;
        if ((unsigned)ky < (unsigned)R) csr_src[atomicAdd(&cur[ky], 1)] = s.y;
        if ((unsigned)kz < (unsigned)R) csr_src[atomicAdd(&cur[kz], 1)] = s.z;
        if ((unsigned)kw < (unsigned)R) csr_src[atomicAdd(&cur[kw], 1)] = s.w;
    }
    if (i < c1) {
        for (int e = i; e < c1 && e < i + 4; ++e) {
            int k = dst[e] - lo;
            if ((unsigned)k < (unsigned)R) csr_src[atomicAdd(&cur[k], 1)] = src[e];
        }
    }
}

// ====== exclusive scan of cnt_in -> row_off; phase3 also emits norm_in AND norm_out ======
__global__ void scan_phase1(const int* __restrict__ cnt, int* __restrict__ blk_sums, int n) {
    int base = blockIdx.x * SCAN_BLK;
    int t = threadIdx.x;
    int sum = 0;
    for (int i = t; i < SCAN_BLK; i += THREADS) {
        int idx = base + i;
        sum += (idx < n) ? cnt[idx] : 0;
    }
    __shared__ int wsum[4];
    for (int off = 32; off > 0; off >>= 1) sum += __shfl_down(sum, off);
    if ((t & 63) == 0) wsum[t >> 6] = sum;
    __syncthreads();
    if (t == 0) blk_sums[blockIdx.x] = wsum[0] + wsum[1] + wsum[2] + wsum[3];
}

__global__ void scan_phase2(int* __restrict__ blk_sums, int nb) {
    __shared__ int s[1024];
    int t = threadIdx.x;
    s[t] = (t < nb) ? blk_sums[t] : 0;
    __syncthreads();
    for (int off = 1; off < 1024; off <<= 1) {
        int v = s[t];
        if (t >= off) v += s[t - off];
        __syncthreads();
        s[t] = v;
        __syncthreads();
    }
    if (t < nb) blk_sums[t] = (t == 0) ? 0 : s[t - 1];
}

__global__ void scan_phase3(const int* __restrict__ cnt, const int* __restrict__ cnt_out,
                            const int* __restrict__ blk_sums,
                            int* __restrict__ row_off, float* __restrict__ norm_in,
                            float* __restrict__ norm_out, int n, int E) {
    __shared__ int ts[THREADS];
    int b = blockIdx.x, t = threadIdx.x;
    int base = b * SCAN_BLK + t * 4;
    int local[4], val[4]; int s = 0;
    #pragma unroll
    for (int k = 0; k < 4; ++k) {
        local[k] = s;
        int idx = base + k;
        int v = (idx < n) ? cnt[idx] : 0;
        val[k] = v;
        s += v;
    }
    ts[t] = s;
    __syncthreads();
    for (int off = 1; off < THREADS; off <<= 1) {
        int v = ts[t];
        if (t >= off) v += ts[t - off];
        __syncthreads();
        ts[t] = v;
        __syncthreads();
    }
    int excl = (t == 0) ? 0 : ts[t - 1];
    int boff = blk_sums[b];
    #pragma unroll
    for (int k = 0; k < 4; ++k) {
        int idx = base + k;
        if (idx < n) {
            row_off[idx] = boff + excl + local[k];
            norm_in[idx]  = rsqrtf((float)max(val[k], 1));
            norm_out[idx] = rsqrtf((float)max(cnt_out[idx], 1));
        }
    }
    if (b == 0 && t == 0) row_off[n] = E;
}

// ====== fused W fragment pre-pack (all 3 weights, one dispatch) ======
__device__ __forceinline__ void wpack_one(const float* __restrict__ W, ushort* __restrict__ Wpk,
                                          int OUT, int t) {
    int lane = t & 63, kk = (t >> 6) & 3, ct = t >> 8;
    int col = ct * 16 + (lane & 15);
    int k0 = kk * 32 + (lane >> 4) * 8;
    #pragma unroll
    for (int j = 0; j < 8; ++j)
        Wpk[t * 8 + j] = f2bf(W[(size_t)(k0 + j) * OUT + col]);
}

__global__ void wpack_all(const float* __restrict__ W1, const float* __restrict__ W2,
                          const float* __restrict__ W3, ushort* __restrict__ Wpk1,
                          ushort* __restrict__ Wpk2, ushort* __restrict__ Wpk3) {
    int t = blockIdx.x * blockDim.x + threadIdx.x;
    if (t < 2048)      wpack_one(W1, Wpk1, 128, t);
    else if (t < 4096) wpack_one(W2, Wpk2, 128, t - 2048);
    else if (t < 5120) wpack_one(W3, Wpk3, 64,  t - 4096);
}

// ====== MFMA GEMM: h = bf16((x*norm) @ W), 64 nodes/block ======
template<int OUT, bool IN_F32>
__global__ __launch_bounds__(256) void mfma_gemm(const void* __restrict__ xv,
                                                 const ushort* __restrict__ Wpk,
                                                 const float* __restrict__ norm,
                                                 ushort* __restrict__ h, int n) {
    __shared__ ushort xs[64 * 136];
    const int t = threadIdx.x;
    const int row0 = blockIdx.x * 64;

    if (IN_F32) {
        const float* x = (const float*)xv;
        #pragma unroll
        for (int i = 0; i < 8; ++i) {
            int e = (i * 256 + t) * 4;
            int row = e >> 7, col = e & 127;
            int gr = min(row0 + row, n - 1);
            float nf = norm[gr];
            float4 v = *(const float4*)(x + (size_t)gr * 128 + col);
            ushort4 p;
            p.x = f2bf(v.x * nf); p.y = f2bf(v.y * nf);
            p.z = f2bf(v.z * nf); p.w = f2bf(v.w * nf);
            *(ushort4*)(&xs[row * 136 + col]) = p;
        }
    } else {
        const ushort* x = (const ushort*)xv;
        #pragma unroll
        for (int i = 0; i < 4; ++i) {
            int e = (i * 256 + t) * 8;
            int row = e >> 7, col = e & 127;
            int gr = min(row0 + row, n - 1);
            float nf = norm[gr];
            uint4 v = *(const uint4*)(x + (size_t)gr * 128 + col);
            uint4 o;
            o.x = f2bf(bf_lo(v.x) * nf) | ((uint)f2bf(bf_hi(v.x) * nf) << 16);
            o.y = f2bf(bf_lo(v.y) * nf) | ((uint)f2bf(bf_hi(v.y) * nf) << 16);
            o.z = f2bf(bf_lo(v.z) * nf) | ((uint)f2bf(bf_hi(v.z) * nf) << 16);
            o.w = f2bf(bf_lo(v.w) * nf) | ((uint)f2bf(bf_hi(v.w) * nf) << 16);
            *(uint4*)(&xs[row * 136 + col]) = o;
        }
    }
    __syncthreads();

    const int wave = t >> 6, lane = t & 63;
    const int r = lane & 15, g = lane >> 4;
    const int nrow0 = row0 + wave * 16;

    short8 a[4];
    #pragma unroll
    for (int kk = 0; kk < 4; ++kk)
        a[kk] = *(const short8*)(&xs[(wave * 16 + r) * 136 + kk * 32 + g * 8]);

    const short8* wp = (const short8*)Wpk;
    #pragma unroll
    for (int ct = 0; ct < OUT / 16; ++ct) {
        floatx4 acc = {0.f, 0.f, 0.f, 0.f};
        #pragma unroll
        for (int kk = 0; kk < 4; ++kk) {
            short8 b = wp[(ct * 4 + kk) * 64 + lane];
            acc = __builtin_amdgcn_mfma_f32_16x16x32_bf16(a[kk], b, acc, 0, 0, 0);
        }
        int col = ct * 16 + r;
        #pragma unroll
        for (int rr = 0; rr < 4; ++rr) {
            int grow = nrow0 + g * 4 + rr;
            if (grow < n) h[(size_t)grow * OUT + col] = f2bf(acc[rr]);
        }
    }
}

// ====== CSR aggregation, 128-wide bf16 in, bf16 out ======
template<bool RELU>
__global__ __launch_bounds__(256) void agg128(const ushort* __restrict__ h,
                                              const int* __restrict__ row_off,
                                              const int* __restrict__ csr_src,
                                              const float* __restrict__ nin,
                                              const float* __restrict__ bias,
                                              ushort* __restrict__ out, int n) {
    const int wave = threadIdx.x >> 6;
    const int lane = threadIdx.x & 63;
    const uint* hu = (const uint*)h;
    for (int node = blockIdx.x * 4 + wave; node < n; node += gridDim.x * 4) {
        int beg = row_off[node], end = row_off[node + 1];
        float a0 = 0.f, a1 = 0.f;
        int j = beg;
        for (; j + 3 < end; j += 4) {
            int s0 = csr_src[j], s1 = csr_src[j + 1], s2 = csr_src[j + 2], s3 = csr_src[j + 3];
            uint u0 = hu[(size_t)s0 * 64 + lane];
            uint u1 = hu[(size_t)s1 * 64 + lane];
            uint u2 = hu[(size_t)s2 * 64 + lane];
            uint u3 = hu[(size_t)s3 * 64 + lane];
            a0 += bf_lo(u0); a1 += bf_hi(u0);
            a0 += bf_lo(u1); a1 += bf_hi(u1);
            a0 += bf_lo(u2); a1 += bf_hi(u2);
            a0 += bf_lo(u3); a1 += bf_hi(u3);
        }
        for (; j < end; ++j) {
            uint u = hu[(size_t)csr_src[j] * 64 + lane];
            a0 += bf_lo(u); a1 += bf_hi(u);
        }
        float nf = nin[node];
        float2 bb = *(const float2*)(bias + 2 * lane);
        float r0 = a0 * nf + bb.x;
        float r1 = a1 * nf + bb.y;
        if (RELU) { r0 = fmaxf(r0, 0.f); r1 = fmaxf(r1, 0.f); }
        ((uint*)out)[(size_t)node * 64 + lane] = (uint)f2bf(r0) | ((uint)f2bf(r1) << 16);
    }
}

// ====== CSR aggregation, 64-wide bf16 in, fp32 out (final layer) ======
__global__ __launch_bounds__(256) void agg64_final(const ushort* __restrict__ h,
                                                   const int* __restrict__ row_off,
                                                   const int* __restrict__ csr_src,
                                                   const float* __restrict__ nin,
                                                   const float* __restrict__ bias,
                                                   float* __restrict__ out, int n) {
    const int wave = threadIdx.x >> 6;
    const int lane = threadIdx.x & 63;
    const int half = lane >> 5, u5 = lane & 31;
    const uint* hu = (const uint*)h;
    for (int node = blockIdx.x * 4 + wave; node < n; node += gridDim.x * 4) {
        int beg = row_off[node], end = row_off[node + 1];
        float a0 = 0.f, a1 = 0.f;
        int j = beg + half;
        for (; j + 2 < end; j += 4) {
            int sA = csr_src[j], sB = csr_src[j + 2];
            uint uA = hu[(size_t)sA * 32 + u5];
            uint uB = hu[(size_t)sB * 32 + u5];
            a0 += bf_lo(uA); a1 += bf_hi(uA);
            a0 += bf_lo(uB); a1 += bf_hi(uB);
        }
        if (j < end) {
            uint u = hu[(size_t)csr_src[j] * 32 + u5];
            a0 += bf_lo(u); a1 += bf_hi(u);
        }
        float o0 = a0 + __shfl(a0, u5 + 32);
        float o1 = a1 + __shfl(a1, u5 + 32);
        if (lane < 32) {
            float nf = nin[node];
            float2 bb = *(const float2*)(bias + 2 * u5);
            float2 r;
            r.x = o0 * nf + bb.x;
            r.y = o1 * nf + bb.y;
            *(float2*)(out + (size_t)node * 64 + 2 * u5) = r;
        }
    }
}

extern "C" void kernel_launch(void* const* d_in, const int* in_sizes, int n_in,
                              void* d_out, int out_size, void* d_ws, size_t ws_size,
                              hipStream_t stream) {
    const float* in_feat = (const float*)d_in[0];
    const int*   src     = (const int*)d_in[1];
    const int*   dst     = (const int*)d_in[2];
    const float* W1      = (const float*)d_in[3];
    const float* b1      = (const float*)d_in[4];
    const float* W2      = (const float*)d_in[5];
    const float* b2      = (const float*)d_in[6];
    const float* W3      = (const float*)d_in[7];
    const float* b3      = (const float*)d_in[8];

    const int n = in_sizes[0] / 128;
    const int E = in_sizes[1];
    float* out = (float*)d_out;

    // ws: norm_out[n], norm_in[n] (f32); row_off[n+4]; csr_src[E]; Wpk1/2/3; bufA, bufB (ushort)
    float* ws       = (float*)d_ws;
    float* norm_out = ws;
    float* norm_in  = ws + n;
    int*   row_off  = (int*)(ws + 2 * (size_t)n);
    int*   csr_src  = row_off + (n + 4);
    ushort* Wpk1    = (ushort*)(csr_src + E);
    ushort* Wpk2    = Wpk1 + 128 * 128;
    ushort* Wpk3    = Wpk2 + 128 * 128;
    ushort* bufA    = Wpk3 + 128 * 64;
    ushort* bufB    = bufA + (size_t)n * 128;
    // CSR-build overlays inside bufA (dead before gemm layer 1 writes bufA):
    int*    cnt_in   = (int*)bufA;                      // n
    int*    cnt_out  = cnt_in + n;                      // n
    int*    blk_sums = cnt_out + n;                     // ~128
    ushort* PC       = (ushort*)(blk_sums + 128);       // NR*NC*RSTRIDE ushorts (6.4 MB)
    int*    Bbase    = (int*)(PC + (size_t)NR * NC * RSTRIDE);  // NR*NC*RSTRIDE ints (12.8 MB)

    const int nb = (n + SCAN_BLK - 1) / SCAN_BLK;

    // ---- CSR build (no global atomics on rank path) + norms + W pack ----
    hipMemsetAsync(cnt_out, 0, (size_t)n * sizeof(int), stream);
    wpack_all<<<20, THREADS, 0, stream>>>(W1, W2, W3, Wpk1, Wpk2, Wpk3);
    hist_out_kernel<<<NR * NC, THREADS, 0, stream>>>(src, cnt_out, n, E);
    csr_phaseA<<<NR * NC, THREADS, 0, stream>>>(dst, PC, n, E);
    csr_colsum<<<(n + THREADS - 1) / THREADS, THREADS, 0, stream>>>(PC, cnt_in, n);
    scan_phase1<<<nb, THREADS, 0, stream>>>(cnt_in, blk_sums, n);
    scan_phase2<<<1, 1024, 0, stream>>>(blk_sums, nb);
    scan_phase3<<<nb, THREADS, 0, stream>>>(cnt_in, cnt_out, blk_sums, row_off, norm_in, norm_out, n, E);
    csr_mkbase<<<(n + THREADS - 1) / THREADS, THREADS, 0, stream>>>(PC, row_off, Bbase, n);
    csr_phaseC<<<NR * NC, THREADS, 0, stream>>>(src, dst, Bbase, csr_src, n, E);

    const int gemm_grid = (n + 63) / 64;
    const int agg_grid  = 4096;

    // ---- layer 1 ----
    mfma_gemm<128, true><<<gemm_grid, THREADS, 0, stream>>>(in_feat, Wpk1, norm_out, bufA, n);
    agg128<true><<<agg_grid, THREADS, 0, stream>>>(bufA, row_off, csr_src, norm_in, b1, bufB, n);
    // ---- layer 2 ----
    mfma_gemm<128, false><<<gemm_grid, THREADS, 0, stream>>>(bufB, Wpk2, norm_out, bufA, n);
    agg128<true><<<agg_grid, THREADS, 0, stream>>>(bufA, row_off, csr_src, norm_in, b2, bufB, n);
    // ---- layer 3 ----
    mfma_gemm<64, false><<<gemm_grid, THREADS, 0, stream>>>(bufB, Wpk3, norm_out, bufA, n);
    agg64_final<<<agg_grid, THREADS, 0, stream>>>(bufA, row_off, csr_src, norm_in, b3, out, n);
}

// Round 11
// 400.783 us; speedup vs baseline: 1.6493x; 1.0415x over previous
//
#include <hip/hip_runtime.h>

#define THREADS 256
#define SCAN_BLK 1024
#define NR 8            // node ranges (counting sort + hist)
#define NC 32           // edge chunks
#define RSTRIDE 12544   // padded per-range node stride (>= ceil(100000/8))

typedef __attribute__((ext_vector_type(8))) _Float16 half8;
typedef __attribute__((ext_vector_type(4))) float floatx4;

__device__ __forceinline__ ushort f2h(float f) {
    union { _Float16 h; ushort s; } v;
    v.h = (_Float16)f;               // v_cvt_f16_f32, RNE
    return v.s;
}
__device__ __forceinline__ float h_lo(uint u) {
    union { ushort s; _Float16 h; } v; v.s = (ushort)(u & 0xFFFFu); return (float)v.h;
}
__device__ __forceinline__ float h_hi(uint u) {
    union { ushort s; _Float16 h; } v; v.s = (ushort)(u >> 16); return (float)v.h;
}

// ====== src out-degree histogram: NR ranges x NC chunks, LDS counts, coalesced merge ======
__global__ __launch_bounds__(256) void hist_out_kernel(const int* __restrict__ src,
                                                       int* __restrict__ cnt_out,
                                                       int n, int E) {
    __shared__ uint cnt[RSTRIDE];
    const int range = blockIdx.x % NR;
    const int chunk = blockIdx.x / NR;
    const int Rsz = (n + NR - 1) / NR;
    const int lo  = range * Rsz;
    const int R   = min(n - lo, Rsz);
    if (R <= 0) return;
    for (int i = threadIdx.x; i < R; i += THREADS) cnt[i] = 0;
    __syncthreads();
    const int per = (E + NC - 1) / NC;
    const int c0 = chunk * per;
    const int c1 = min(E, c0 + per);
    int i = c0 + threadIdx.x * 4;
    for (; i + 4 <= c1; i += THREADS * 4) {
        int4 v = *(const int4*)(src + i);
        if ((unsigned)(v.x - lo) < (unsigned)R) atomicAdd(&cnt[v.x - lo], 1u);
        if ((unsigned)(v.y - lo) < (unsigned)R) atomicAdd(&cnt[v.y - lo], 1u);
        if ((unsigned)(v.z - lo) < (unsigned)R) atomicAdd(&cnt[v.z - lo], 1u);
        if ((unsigned)(v.w - lo) < (unsigned)R) atomicAdd(&cnt[v.w - lo], 1u);
    }
    if (i < c1) {
        for (int e = i; e < c1 && e < i + 4; ++e) {
            int s = src[e];
            if ((unsigned)(s - lo) < (unsigned)R) atomicAdd(&cnt[s - lo], 1u);
        }
    }
    __syncthreads();
    for (int k = threadIdx.x; k < R; k += THREADS) {
        uint c = cnt[k];
        if (c) atomicAdd(&cnt_out[lo + k], (int)c);
    }
}

// ====== counting-sort phase A: per-(range,chunk) dst histogram -> PC (ushort) ======
__global__ __launch_bounds__(256) void csr_phaseA(const int* __restrict__ dst,
                                                  ushort* __restrict__ PC, int n, int E) {
    __shared__ uint cnt[RSTRIDE / 2];
    const int range = blockIdx.x % NR;
    const int chunk = blockIdx.x / NR;
    const int Rsz = (n + NR - 1) / NR;
    const int lo  = range * Rsz;
    const int R   = min(n - lo, Rsz);
    if (R <= 0) return;
    const int Rp = (R + 2) >> 1;
    for (int i = threadIdx.x; i < Rp; i += THREADS) cnt[i] = 0;
    __syncthreads();
    const int per = (E + NC - 1) / NC;
    const int c0 = chunk * per;
    const int c1 = min(E, c0 + per);
    int i = c0 + threadIdx.x * 4;
    for (; i + 4 <= c1; i += THREADS * 4) {
        int4 v = *(const int4*)(dst + i);
        int kx = v.x - lo, ky = v.y - lo, kz = v.z - lo, kw = v.w - lo;
        if ((unsigned)kx < (unsigned)R) atomicAdd(&cnt[kx >> 1], (kx & 1) ? 65536u : 1u);
        if ((unsigned)ky < (unsigned)R) atomicAdd(&cnt[ky >> 1], (ky & 1) ? 65536u : 1u);
        if ((unsigned)kz < (unsigned)R) atomicAdd(&cnt[kz >> 1], (kz & 1) ? 65536u : 1u);
        if ((unsigned)kw < (unsigned)R) atomicAdd(&cnt[kw >> 1], (kw & 1) ? 65536u : 1u);
    }
    if (i < c1) {
        for (int e = i; e < c1 && e < i + 4; ++e) {
            int k = dst[e] - lo;
            if ((unsigned)k < (unsigned)R) atomicAdd(&cnt[k >> 1], (k & 1) ? 65536u : 1u);
        }
    }
    __syncthreads();
    ushort* pc = PC + (size_t)(range * NC + chunk) * RSTRIDE;
    for (int k = threadIdx.x; k < R; k += THREADS) {
        uint c = cnt[k >> 1];
        pc[k] = (ushort)((k & 1) ? (c >> 16) : (c & 0xFFFFu));
    }
}

// ====== colsum: cnt_in[node] = sum over chunks of PC ======
__global__ void csr_colsum(const ushort* __restrict__ PC, int* __restrict__ cnt_in, int n) {
    int gk = blockIdx.x * blockDim.x + threadIdx.x;
    if (gk >= n) return;
    const int Rsz = (n + NR - 1) / NR;
    int r = gk / Rsz, k = gk - r * Rsz;
    int t = 0;
    #pragma unroll 4
    for (int c = 0; c < NC; ++c)
        t += PC[(size_t)(r * NC + c) * RSTRIDE + k];
    cnt_in[gk] = t;
}

// ====== mkbase: B[r][c][k] = row_off[node] + prefix_{c'<c} PC ======
__global__ void csr_mkbase(const ushort* __restrict__ PC, const int* __restrict__ row_off,
                           int* __restrict__ B, int n) {
    int gk = blockIdx.x * blockDim.x + threadIdx.x;
    if (gk >= n) return;
    const int Rsz = (n + NR - 1) / NR;
    int r = gk / Rsz, k = gk - r * Rsz;
    int base = row_off[gk];
    for (int c = 0; c < NC; ++c) {
        size_t idx = (size_t)(r * NC + c) * RSTRIDE + k;
        B[idx] = base;
        base += PC[idx];
    }
}

// ====== counting-sort phase C: LDS cursors, scatter csr_src (no global atomics) ======
__global__ __launch_bounds__(256) void csr_phaseC(const int* __restrict__ src,
                                                  const int* __restrict__ dst,
                                                  const int* __restrict__ B,
                                                  int* __restrict__ csr_src, int n, int E) {
    __shared__ int cur[RSTRIDE];
    const int range = blockIdx.x % NR;
    const int chunk = blockIdx.x / NR;
    const int Rsz = (n + NR - 1) / NR;
    const int lo  = range * Rsz;
    const int R   = min(n - lo, Rsz);
    if (R <= 0) return;
    const int* b = B + (size_t)(range * NC + chunk) * RSTRIDE;
    for (int i = threadIdx.x; i < R; i += THREADS) cur[i] = b[i];
    __syncthreads();
    const int per = (E + NC - 1) / NC;
    const int c0 = chunk * per;
    const int c1 = min(E, c0 + per);
    int i = c0 + threadIdx.x * 4;
    for (; i + 4 <= c1; i += THREADS * 4) {
        int4 d = *(const int4*)(dst + i);
        int4 s = *(const int4*)(src + i);
        int kx = d.x - lo, ky = d.y - lo, kz = d.z - lo, kw = d.w - lo;
        if ((unsigned)kx < (unsigned)R) csr_src[atomicAdd(&cur[kx], 1)] = s.x;
        if ((unsigned)ky < (unsigned)R) csr_src[atomicAdd(&cur[ky], 1)] = s.y;
        if ((unsigned)kz < (unsigned)R) csr_src[atomicAdd(&cur[kz], 1)] = s.z;
        if ((unsigned)kw < (unsigned)R) csr_src[atomicAdd(&cur[kw], 1)] = s.w;
    }
    if (i < c1) {
        for (int e = i; e < c1 && e < i + 4; ++e) {
            int k = dst[e] - lo;
            if ((unsigned)k < (unsigned)R) csr_src[atomicAdd(&cur[k], 1)] = src[e];
        }
    }
}

// ====== exclusive scan of cnt_in -> row_off; phase3 also emits norm_in AND norm_out ======
__global__ void scan_phase1(const int* __restrict__ cnt, int* __restrict__ blk_sums, int n) {
    int base = blockIdx.x * SCAN_BLK;
    int t = threadIdx.x;
    int sum = 0;
    for (int i = t; i < SCAN_BLK; i += THREADS) {
        int idx = base + i;
        sum += (idx < n) ? cnt[idx] : 0;
    }
    __shared__ int wsum[4];
    for (int off = 32; off > 0; off >>= 1) sum += __shfl_down(sum, off);
    if ((t & 63) == 0) wsum[t >> 6] = sum;
    __syncthreads();
    if (t == 0) blk_sums[blockIdx.x] = wsum[0] + wsum[1] + wsum[2] + wsum[3];
}

__global__ void scan_phase2(int* __restrict__ blk_sums, int nb) {
    __shared__ int s[1024];
    int t = threadIdx.x;
    s[t] = (t < nb) ? blk_sums[t] : 0;
    __syncthreads();
    for (int off = 1; off < 1024; off <<= 1) {
        int v = s[t];
        if (t >= off) v += s[t - off];
        __syncthreads();
        s[t] = v;
        __syncthreads();
    }
    if (t < nb) blk_sums[t] = (t == 0) ? 0 : s[t - 1];
}

__global__ void scan_phase3(const int* __restrict__ cnt, const int* __restrict__ cnt_out,
                            const int* __restrict__ blk_sums,
                            int* __restrict__ row_off, float* __restrict__ norm_in,
                            float* __restrict__ norm_out, int n, int E) {
    __shared__ int ts[THREADS];
    int b = blockIdx.x, t = threadIdx.x;
    int base = b * SCAN_BLK + t * 4;
    int local[4], val[4]; int s = 0;
    #pragma unroll
    for (int k = 0; k < 4; ++k) {
        local[k] = s;
        int idx = base + k;
        int v = (idx < n) ? cnt[idx] : 0;
        val[k] = v;
        s += v;
    }
    ts[t] = s;
    __syncthreads();
    for (int off = 1; off < THREADS; off <<= 1) {
        int v = ts[t];
        if (t >= off) v += ts[t - off];
        __syncthreads();
        ts[t] = v;
        __syncthreads();
    }
    int excl = (t == 0) ? 0 : ts[t - 1];
    int boff = blk_sums[b];
    #pragma unroll
    for (int k = 0; k < 4; ++k) {
        int idx = base + k;
        if (idx < n) {
            row_off[idx] = boff + excl + local[k];
            norm_in[idx]  = rsqrtf((float)max(val[k], 1));
            norm_out[idx] = rsqrtf((float)max(cnt_out[idx], 1));
        }
    }
    if (b == 0 && t == 0) row_off[n] = E;
}

// ====== fused W fragment pre-pack (all 3 weights, one dispatch, fp16) ======
__device__ __forceinline__ void wpack_one(const float* __restrict__ W, ushort* __restrict__ Wpk,
                                          int OUT, int t) {
    int lane = t & 63, kk = (t >> 6) & 3, ct = t >> 8;
    int col = ct * 16 + (lane & 15);
    int k0 = kk * 32 + (lane >> 4) * 8;
    #pragma unroll
    for (int j = 0; j < 8; ++j)
        Wpk[t * 8 + j] = f2h(W[(size_t)(k0 + j) * OUT + col]);
}

__global__ void wpack_all(const float* __restrict__ W1, const float* __restrict__ W2,
                          const float* __restrict__ W3, ushort* __restrict__ Wpk1,
                          ushort* __restrict__ Wpk2, ushort* __restrict__ Wpk3) {
    int t = blockIdx.x * blockDim.x + threadIdx.x;
    if (t < 2048)      wpack_one(W1, Wpk1, 128, t);
    else if (t < 4096) wpack_one(W2, Wpk2, 128, t - 2048);
    else if (t < 5120) wpack_one(W3, Wpk3, 64,  t - 4096);
}

// ====== MFMA GEMM (layer 1 only): h = fp16((x*norm) @ W), 64 nodes/block ======
template<int OUT>
__global__ __launch_bounds__(256) void mfma_gemm(const float* __restrict__ x,
                                                 const ushort* __restrict__ Wpk,
                                                 const float* __restrict__ norm,
                                                 ushort* __restrict__ h, int n) {
    __shared__ ushort xs[64 * 136];
    const int t = threadIdx.x;
    const int row0 = blockIdx.x * 64;

    #pragma unroll
    for (int i = 0; i < 8; ++i) {
        int e = (i * 256 + t) * 4;
        int row = e >> 7, col = e & 127;
        int gr = min(row0 + row, n - 1);
        float nf = norm[gr];
        float4 v = *(const float4*)(x + (size_t)gr * 128 + col);
        ushort4 p;
        p.x = f2h(v.x * nf); p.y = f2h(v.y * nf);
        p.z = f2h(v.z * nf); p.w = f2h(v.w * nf);
        *(ushort4*)(&xs[row * 136 + col]) = p;
    }
    __syncthreads();

    const int wave = t >> 6, lane = t & 63;
    const int r = lane & 15, g = lane >> 4;
    const int nrow0 = row0 + wave * 16;

    half8 a[4];
    #pragma unroll
    for (int kk = 0; kk < 4; ++kk)
        a[kk] = *(const half8*)(&xs[(wave * 16 + r) * 136 + kk * 32 + g * 8]);

    const half8* wp = (const half8*)Wpk;
    #pragma unroll
    for (int ct = 0; ct < OUT / 16; ++ct) {
        floatx4 acc = {0.f, 0.f, 0.f, 0.f};
        #pragma unroll
        for (int kk = 0; kk < 4; ++kk) {
            half8 b = wp[(ct * 4 + kk) * 64 + lane];
            acc = __builtin_amdgcn_mfma_f32_16x16x32_f16(a[kk], b, acc, 0, 0, 0);
        }
        int col = ct * 16 + r;
        #pragma unroll
        for (int rr = 0; rr < 4; ++rr) {
            int grow = nrow0 + g * 4 + rr;
            if (grow < n) h[(size_t)grow * OUT + col] = f2h(acc[rr]);
        }
    }
}

// ====== FUSED: agg (128-wide fp16) + finalize + next-layer GEMM (128 -> OUTN) ======
template<int OUTN>
__global__ __launch_bounds__(256) void fused_agg_gemm(const ushort* __restrict__ h,
                                                      const int* __restrict__ row_off,
                                                      const int* __restrict__ csr_src,
                                                      const float* __restrict__ nin,
                                                      const float* __restrict__ bias,
                                                      const float* __restrict__ nout,
                                                      const ushort* __restrict__ Wpk,
                                                      ushort* __restrict__ h_next, int n) {
    __shared__ ushort xs[64 * 136];
    const int t = threadIdx.x;
    const int wave = t >> 6, lane = t & 63;
    const int row0 = blockIdx.x * 64;
    const uint* hu = (const uint*)h;
    const float2 bb = *(const float2*)(bias + 2 * lane);

    for (int i = 0; i < 16; ++i) {
        const int lrow = wave * 16 + i;
        const int node = row0 + lrow;
        float a0 = 0.f, a1 = 0.f;
        if (node < n) {
            int beg = row_off[node], end = row_off[node + 1];
            int j = beg;
            for (; j + 3 < end; j += 4) {
                int s0 = csr_src[j], s1 = csr_src[j + 1], s2 = csr_src[j + 2], s3 = csr_src[j + 3];
                uint u0 = hu[(size_t)s0 * 64 + lane];
                uint u1 = hu[(size_t)s1 * 64 + lane];
                uint u2 = hu[(size_t)s2 * 64 + lane];
                uint u3 = hu[(size_t)s3 * 64 + lane];
                a0 += h_lo(u0); a1 += h_hi(u0);
                a0 += h_lo(u1); a1 += h_hi(u1);
                a0 += h_lo(u2); a1 += h_hi(u2);
                a0 += h_lo(u3); a1 += h_hi(u3);
            }
            for (; j < end; ++j) {
                uint u = hu[(size_t)csr_src[j] * 64 + lane];
                a0 += h_lo(u); a1 += h_hi(u);
            }
            float nf = nin[node];
            a0 = fmaxf(a0 * nf + bb.x, 0.f);       // relu (layers 1,2 both have relu)
            a1 = fmaxf(a1 * nf + bb.y, 0.f);
            float no = nout[node];
            a0 *= no; a1 *= no;
        }
        ((uint*)xs)[lrow * 68 + lane] = (uint)f2h(a0) | ((uint)f2h(a1) << 16);
    }
    __syncthreads();

    const int r = lane & 15, g = lane >> 4;
    const int nrow0 = row0 + wave * 16;

    half8 a[4];
    #pragma unroll
    for (int kk = 0; kk < 4; ++kk)
        a[kk] = *(const half8*)(&xs[(wave * 16 + r) * 136 + kk * 32 + g * 8]);

    const half8* wp = (const half8*)Wpk;
    #pragma unroll
    for (int ct = 0; ct < OUTN / 16; ++ct) {
        floatx4 acc = {0.f, 0.f, 0.f, 0.f};
        #pragma unroll
        for (int kk = 0; kk < 4; ++kk) {
            half8 b = wp[(ct * 4 + kk) * 64 + lane];
            acc = __builtin_amdgcn_mfma_f32_16x16x32_f16(a[kk], b, acc, 0, 0, 0);
        }
        int col = ct * 16 + r;
        #pragma unroll
        for (int rr = 0; rr < 4; ++rr) {
            int grow = nrow0 + g * 4 + rr;
            if (grow < n) h_next[(size_t)grow * OUTN + col] = f2h(acc[rr]);
        }
    }
}

// ====== CSR aggregation, 64-wide fp16 in, fp32 out (final layer) ======
__global__ __launch_bounds__(256) void agg64_final(const ushort* __restrict__ h,
                                                   const int* __restrict__ row_off,
                                                   const int* __restrict__ csr_src,
                                                   const float* __restrict__ nin,
                                                   const float* __restrict__ bias,
                                                   float* __restrict__ out, int n) {
    const int wave = threadIdx.x >> 6;
    const int lane = threadIdx.x & 63;
    const int half = lane >> 5, u5 = lane & 31;
    const uint* hu = (const uint*)h;
    for (int node = blockIdx.x * 4 + wave; node < n; node += gridDim.x * 4) {
        int beg = row_off[node], end = row_off[node + 1];
        float a0 = 0.f, a1 = 0.f;
        int j = beg + half;
        for (; j + 2 < end; j += 4) {
            int sA = csr_src[j], sB = csr_src[j + 2];
            uint uA = hu[(size_t)sA * 32 + u5];
            uint uB = hu[(size_t)sB * 32 + u5];
            a0 += h_lo(uA); a1 += h_hi(uA);
            a0 += h_lo(uB); a1 += h_hi(uB);
        }
        if (j < end) {
            uint u = hu[(size_t)csr_src[j] * 32 + u5];
            a0 += h_lo(u); a1 += h_hi(u);
        }
        float o0 = a0 + __shfl(a0, u5 + 32);
        float o1 = a1 + __shfl(a1, u5 + 32);
        if (lane < 32) {
            float nf = nin[node];
            float2 bb = *(const float2*)(bias + 2 * u5);
            float2 r;
            r.x = o0 * nf + bb.x;
            r.y = o1 * nf + bb.y;
            *(float2*)(out + (size_t)node * 64 + 2 * u5) = r;
        }
    }
}

extern "C" void kernel_launch(void* const* d_in, const int* in_sizes, int n_in,
                              void* d_out, int out_size, void* d_ws, size_t ws_size,
                              hipStream_t stream) {
    const float* in_feat = (const float*)d_in[0];
    const int*   src     = (const int*)d_in[1];
    const int*   dst     = (const int*)d_in[2];
    const float* W1      = (const float*)d_in[3];
    const float* b1      = (const float*)d_in[4];
    const float* W2      = (const float*)d_in[5];
    const float* b2      = (const float*)d_in[6];
    const float* W3      = (const float*)d_in[7];
    const float* b3      = (const float*)d_in[8];

    const int n = in_sizes[0] / 128;
    const int E = in_sizes[1];
    float* out = (float*)d_out;

    // ws: norm_out[n], norm_in[n] (f32); row_off[n+4]; csr_src[E]; Wpk1/2/3; bufA, bufB (ushort)
    float* ws       = (float*)d_ws;
    float* norm_out = ws;
    float* norm_in  = ws + n;
    int*   row_off  = (int*)(ws + 2 * (size_t)n);
    int*   csr_src  = row_off + (n + 4);
    ushort* Wpk1    = (ushort*)(csr_src + E);
    ushort* Wpk2    = Wpk1 + 128 * 128;
    ushort* Wpk3    = Wpk2 + 128 * 128;
    ushort* bufA    = Wpk3 + 128 * 64;
    ushort* bufB    = bufA + (size_t)n * 128;
    // CSR-build overlays inside bufA (dead before gemm layer 1 writes bufA):
    int*    cnt_in   = (int*)bufA;                      // n
    int*    cnt_out  = cnt_in + n;                      // n
    int*    blk_sums = cnt_out + n;                     // ~128
    ushort* PC       = (ushort*)(blk_sums + 128);       // NR*NC*RSTRIDE ushorts (6.4 MB)
    int*    Bbase    = (int*)(PC + (size_t)NR * NC * RSTRIDE);  // NR*NC*RSTRIDE ints (12.8 MB)

    const int nb = (n + SCAN_BLK - 1) / SCAN_BLK;

    // ---- CSR build (no global atomics on rank path) + norms + W pack ----
    hipMemsetAsync(cnt_out, 0, (size_t)n * sizeof(int), stream);
    wpack_all<<<20, THREADS, 0, stream>>>(W1, W2, W3, Wpk1, Wpk2, Wpk3);
    hist_out_kernel<<<NR * NC, THREADS, 0, stream>>>(src, cnt_out, n, E);
    csr_phaseA<<<NR * NC, THREADS, 0, stream>>>(dst, PC, n, E);
    csr_colsum<<<(n + THREADS - 1) / THREADS, THREADS, 0, stream>>>(PC, cnt_in, n);
    scan_phase1<<<nb, THREADS, 0, stream>>>(cnt_in, blk_sums, n);
    scan_phase2<<<1, 1024, 0, stream>>>(blk_sums, nb);
    scan_phase3<<<nb, THREADS, 0, stream>>>(cnt_in, cnt_out, blk_sums, row_off, norm_in, norm_out, n, E);
    csr_mkbase<<<(n + THREADS - 1) / THREADS, THREADS, 0, stream>>>(PC, row_off, Bbase, n);
    csr_phaseC<<<NR * NC, THREADS, 0, stream>>>(src, dst, Bbase, csr_src, n, E);

    const int tile_grid = (n + 63) / 64;
    const int agg_grid  = 4096;

    // ---- layer 1 GEMM ----
    mfma_gemm<128><<<tile_grid, THREADS, 0, stream>>>(in_feat, Wpk1, norm_out, bufA, n);
    // ---- agg1 + gemm2 fused ----
    fused_agg_gemm<128><<<tile_grid, THREADS, 0, stream>>>(bufA, row_off, csr_src, norm_in, b1,
                                                           norm_out, Wpk2, bufB, n);
    // ---- agg2 + gemm3 fused ----
    fused_agg_gemm<64><<<tile_grid, THREADS, 0, stream>>>(bufB, row_off, csr_src, norm_in, b2,
                                                          norm_out, Wpk3, bufA, n);
    // ---- final agg (64-wide, fp32 out) ----
    agg64_final<<<agg_grid, THREADS, 0, stream>>>(bufA, row_off, csr_src, norm_in, b3, out, n);
}